// Round 3
// baseline (480.760 us; speedup 1.0000x reference)
//
#include <hip/hip_runtime.h>

#define NSLOPE  0.2f

__device__ __forceinline__ unsigned bf16_rne(float f) {
    unsigned x = __float_as_uint(f);
    return (x + 0x7fffu + ((x >> 16) & 1u)) >> 16;
}

// ---------------- Kernel 1: h = x @ W^T, fused attention dots ----------------
// W (128x128) staged in LDS padded to stride 132 (conflict-free float4 reads).
// Each wave processes 4 nodes per iteration; lane l owns channels l and l+64.
// h is stored packed: h2[n*64 + l] = (bf16(h[n][l]) | bf16(h[n][64+l])<<16).
__global__ __launch_bounds__(256) void k_gemm_att(
    const float* __restrict__ x, const float* __restrict__ Wg,
    const float* __restrict__ att_src, const float* __restrict__ att_dst,
    unsigned* __restrict__ h2, float* __restrict__ a_src, float* __restrict__ a_dst,
    int N)
{
    __shared__ float Wl[128 * 132];
    __shared__ float xl[4][4][128];

    const int t = threadIdx.x;
    const int wave = t >> 6, l = t & 63;

    // stage W: 128x128 floats as float4, coalesced
    for (int i = t; i < 128 * 32; i += 256) {
        int r = i >> 5, c4 = (i & 31) * 4;
        float4 w = *(const float4*)(Wg + r * 128 + c4);
        *(float4*)(&Wl[r * 132 + c4]) = w;
    }

    const float as0 = att_src[l],      as1 = att_src[64 + l];
    const float ad0 = att_dst[l],      ad1 = att_dst[64 + l];

    __syncthreads();

    const int stride = gridDim.x * 16;
    for (int cb = blockIdx.x * 16; cb < N; cb += stride) {
        const int nb = cb + wave * 4;   // this wave's 4 nodes
        // stage x rows (4 per wave): lane loads 2 float4
        {
            int r0 = (4 * l) >> 7, c0 = (4 * l) & 127;
            int n0 = nb + r0;
            float4 v0 = (n0 < N) ? *(const float4*)(x + (size_t)n0 * 128 + c0)
                                 : make_float4(0.f, 0.f, 0.f, 0.f);
            *(float4*)(&xl[wave][r0][c0]) = v0;
            int r1 = r0 + 2;
            int n1 = nb + r1;
            float4 v1 = (n1 < N) ? *(const float4*)(x + (size_t)n1 * 128 + c0)
                                 : make_float4(0.f, 0.f, 0.f, 0.f);
            *(float4*)(&xl[wave][r1][c0]) = v1;
        }
        __syncthreads();

        float acc[4][2];
        #pragma unroll
        for (int i = 0; i < 4; ++i) { acc[i][0] = 0.f; acc[i][1] = 0.f; }

        const float* wr0 = &Wl[(size_t)l * 132];
        const float* wr1 = &Wl[(size_t)(l + 64) * 132];

        #pragma unroll 8
        for (int f = 0; f < 128; f += 4) {
            float4 w0 = *(const float4*)(wr0 + f);
            float4 w1 = *(const float4*)(wr1 + f);
            #pragma unroll
            for (int i = 0; i < 4; ++i) {
                float4 xv = *(const float4*)(&xl[wave][i][f]);
                acc[i][0] += xv.x * w0.x + xv.y * w0.y + xv.z * w0.z + xv.w * w0.w;
                acc[i][1] += xv.x * w1.x + xv.y * w1.y + xv.z * w1.z + xv.w * w1.w;
            }
        }

        #pragma unroll
        for (int i = 0; i < 4; ++i) {
            int node = nb + i;
            if (node >= N) continue;   // uniform across the wave
            float h0 = acc[i][0], h1 = acc[i][1];
            h2[(size_t)node * 64 + l] = bf16_rne(h0) | (bf16_rne(h1) << 16);
            // attention dots (fp32): reduce within 32-lane halves
            float ps = h0 * as0, pd = h0 * ad0;   // heads (l>>5) -> 0/1
            float qs = h1 * as1, qd = h1 * ad1;   // heads 2+(l>>5) -> 2/3
            #pragma unroll
            for (int m = 1; m < 32; m <<= 1) {
                ps += __shfl_xor(ps, m); pd += __shfl_xor(pd, m);
                qs += __shfl_xor(qs, m); qd += __shfl_xor(qd, m);
            }
            if (l == 0) {
                a_src[node * 4 + 0] = ps; a_dst[node * 4 + 0] = pd;
                a_src[node * 4 + 2] = qs; a_dst[node * 4 + 2] = qd;
            } else if (l == 32) {
                a_src[node * 4 + 1] = ps; a_dst[node * 4 + 1] = pd;
                a_src[node * 4 + 3] = qs; a_dst[node * 4 + 3] = qd;
            }
        }
        __syncthreads();
    }
}

// ---------------- Kernel 2: in-degree histogram ----------------
__global__ void k_hist(const int* __restrict__ dst, int* __restrict__ deg, int E)
{
    int i = blockIdx.x * blockDim.x + threadIdx.x;
    int stride = gridDim.x * blockDim.x;
    for (; i < E; i += stride) atomicAdd(&deg[dst[i]], 1);
}

// ---------------- Kernel 3a: per-block local exclusive scan (1024 elems/block)
__global__ __launch_bounds__(256) void k_scan_local(
    const int* __restrict__ deg, int* __restrict__ loc,
    int* __restrict__ partial, int N)
{
    __shared__ int wsum[4];
    const int t = threadIdx.x;
    const int base = blockIdx.x * 1024 + t * 4;

    int v0 = 0, v1 = 0, v2 = 0, v3 = 0;
    if (base + 3 < N) {
        int4 d = *(const int4*)(deg + base);
        v0 = d.x; v1 = d.y; v2 = d.z; v3 = d.w;
    } else if (base < N) {
        v0 = deg[base];
        if (base + 1 < N) v1 = deg[base + 1];
        if (base + 2 < N) v2 = deg[base + 2];
    }
    const int s = v0 + v1 + v2 + v3;

    // inclusive wave scan of per-thread sums
    const int l = t & 63;
    int sc = s;
    #pragma unroll
    for (int m = 1; m < 64; m <<= 1) {
        int u = __shfl_up(sc, m);
        if (l >= m) sc += u;
    }
    if (l == 63) wsum[t >> 6] = sc;
    __syncthreads();

    int woff = 0;
    const int w = t >> 6;
    #pragma unroll
    for (int i = 0; i < 4; ++i) if (i < w) woff += wsum[i];

    const int excl = woff + sc - s;   // exclusive prefix of this thread's 4
    if (base < N) {
        int o0 = excl, o1 = o0 + v0, o2 = o1 + v1, o3 = o2 + v2;
        if (base + 3 < N) {
            *(int4*)(loc + base) = make_int4(o0, o1, o2, o3);
        } else {
            loc[base] = o0;
            if (base + 1 < N) loc[base + 1] = o1;
            if (base + 2 < N) loc[base + 2] = o2;
        }
    }
    if (t == 255) partial[blockIdx.x] = woff + sc;   // block total
}

// ---------------- Kernel 3b: single-wave scan of block totals ----------------
__global__ __launch_bounds__(64) void k_scan_part(
    int* __restrict__ partial, int* __restrict__ total_out, int nb)
{
    const int l = threadIdx.x;
    int carry = 0;
    for (int base = 0; base < nb; base += 64) {
        int i = base + l;
        int v = (i < nb) ? partial[i] : 0;
        int sc = v;
        #pragma unroll
        for (int m = 1; m < 64; m <<= 1) {
            int u = __shfl_up(sc, m);
            if (l >= m) sc += u;
        }
        if (i < nb) partial[i] = carry + sc - v;   // exclusive
        carry += __shfl(sc, 63);
    }
    if (l == 0) *total_out = carry;   // rowptr[N]
}

// ---------------- Kernel 3c: add block offsets, write rowptr & cursor -------
__global__ __launch_bounds__(256) void k_scan_add(
    const int* __restrict__ loc, const int* __restrict__ partial,
    int* __restrict__ rowptr, int* __restrict__ cursor, int N)
{
    const int off = partial[blockIdx.x];
    const int base = blockIdx.x * 1024 + threadIdx.x * 4;
    if (base + 3 < N) {
        int4 v = *(const int4*)(loc + base);
        v.x += off; v.y += off; v.z += off; v.w += off;
        *(int4*)(rowptr + base) = v;
        *(int4*)(cursor + base) = v;
    } else if (base < N) {
        for (int i = base; i < N && i < base + 4; ++i) {
            int v = loc[i] + off;
            rowptr[i] = v; cursor[i] = v;
        }
    }
}

// ---------------- Kernel 4: scatter src ids into CSR ----------------
__global__ void k_scatter(const int* __restrict__ ei, int* __restrict__ cursor,
                          int* __restrict__ csr, int E)
{
    int i = blockIdx.x * blockDim.x + threadIdx.x;
    int stride = gridDim.x * blockDim.x;
    for (; i < E; i += stride) {
        int s = ei[i];
        int d = ei[E + i];
        int pos = atomicAdd(&cursor[d], 1);
        csr[pos] = s;
    }
}

// ---------------- Kernel 5: single-pass softmax-aggregate + classifier -------
// One wave per node. Online (unnormalized) softmax: accumulate exp-weighted
// messages and the denominator in one sweep, normalize at the end.
// Lane layout per 16-edge chunk: edge = l>>2, head = l&3 -> one wave-wide exp
// computes all 64 alphas; per-edge alphas distributed via shfl (LDS pipe).
__global__ __launch_bounds__(256) void k_agg(
    const unsigned* __restrict__ h2, const float* __restrict__ a_src,
    const float* __restrict__ a_dst, const int* __restrict__ rowptr,
    const int* __restrict__ csr, const float* __restrict__ b_gat,
    const float* __restrict__ W_lin, const float* __restrict__ b_lin,
    float* __restrict__ out, int N)
{
    const int t = threadIdx.x;
    const int wave = t >> 6, l = t & 63;
    const int n = blockIdx.x * 4 + wave;
    if (n >= N) return;

    const int start = rowptr[n], end = rowptr[n + 1];
    const int hq = l & 3;            // head this lane computes alphas for
    const int hA = l >> 5;           // head of channel l       (0 or 1)
    const int hB = 2 + hA;           // head of channel 64+l    (2 or 3)
    const int e  = l >> 2;           // edge slot 0..15
    const float ad_q = a_dst[n * 4 + hq];

    float acc0 = 0.f, acc1 = 0.f, dpart = 0.f;

    int i = start;
    for (; i + 16 <= end; i += 16) {           // full chunks, unrolled x16
        int se = csr[i + e];
        float ev = a_src[se * 4 + hq] + ad_q;
        ev = (ev >= 0.f) ? ev : NSLOPE * ev;
        float p = __expf(ev);
        dpart += p;
        #pragma unroll
        for (int k = 0; k < 16; ++k) {
            int   sk = __shfl(se, 4 * k);
            float aA = __shfl(p, 4 * k + hA);
            float aB = __shfl(p, 4 * k + hB);
            unsigned u = h2[(size_t)sk * 64 + l];
            acc0 += aA * __uint_as_float(u << 16);
            acc1 += aB * __uint_as_float(u & 0xffff0000u);
        }
    }
    const int rem = end - i;
    if (rem > 0) {                              // remainder chunk (1..15)
        int se = 0; float p = 0.f;
        if (e < rem) {
            se = csr[i + e];
            float ev = a_src[se * 4 + hq] + ad_q;
            ev = (ev >= 0.f) ? ev : NSLOPE * ev;
            p = __expf(ev);
        }
        dpart += p;
        for (int k = 0; k < rem; ++k) {
            int   sk = __shfl(se, 4 * k);
            float aA = __shfl(p, 4 * k + hA);
            float aB = __shfl(p, 4 * k + hB);
            unsigned u = h2[(size_t)sk * 64 + l];
            acc0 += aA * __uint_as_float(u << 16);
            acc1 += aB * __uint_as_float(u & 0xffff0000u);
        }
    }

    // self-loop term
    float evs = a_src[n * 4 + hq] + ad_q;
    evs = (evs >= 0.f) ? evs : NSLOPE * evs;
    const float ps = __expf(evs);

    // denominator: sum dpart over the 16 edge-slots of each head
    dpart += __shfl_xor(dpart, 4);
    dpart += __shfl_xor(dpart, 8);
    dpart += __shfl_xor(dpart, 16);
    dpart += __shfl_xor(dpart, 32);
    const float den = dpart + ps;    // lane holds denom for head (l&3)

    {   // self-loop contribution
        const float aSA = __shfl(ps, hA), aSB = __shfl(ps, hB);
        unsigned u = h2[(size_t)n * 64 + l];
        acc0 += aSA * __uint_as_float(u << 16);
        acc1 += aSB * __uint_as_float(u & 0xffff0000u);
    }
    acc0 *= 1.f / __shfl(den, hA);
    acc1 *= 1.f / __shfl(den, hB);

    // ---- fused epilogue: +b_gat, ReLU, Linear(128->2), wave reduce ----
    float r0 = fmaxf(acc0 + b_gat[l], 0.f);
    float r1 = fmaxf(acc1 + b_gat[64 + l], 0.f);
    float p0 = r0 * W_lin[l]       + r1 * W_lin[64 + l];
    float p1 = r0 * W_lin[128 + l] + r1 * W_lin[192 + l];
    #pragma unroll
    for (int m = 1; m < 64; m <<= 1) {
        p0 += __shfl_xor(p0, m);
        p1 += __shfl_xor(p1, m);
    }
    if (l == 0) {
        out[(size_t)n * 2]     = p0 + b_lin[0];
        out[(size_t)n * 2 + 1] = p1 + b_lin[1];
    }
}

// ---------------- launch ----------------
extern "C" void kernel_launch(void* const* d_in, const int* in_sizes, int n_in,
                              void* d_out, int out_size, void* d_ws, size_t ws_size,
                              hipStream_t stream)
{
    const float* x       = (const float*)d_in[0];
    const int*   ei      = (const int*)d_in[1];
    const float* Wg      = (const float*)d_in[2];
    const float* att_src = (const float*)d_in[3];
    const float* att_dst = (const float*)d_in[4];
    const float* b_gat   = (const float*)d_in[5];
    const float* W_lin   = (const float*)d_in[6];
    const float* b_lin   = (const float*)d_in[7];
    float* out = (float*)d_out;

    const int N = in_sizes[0] / 128;
    const int E = in_sizes[1] / 2;
    const int NB = (N + 1023) / 1024;   // scan blocks

    // workspace layout (int4/float4 regions 16B aligned)
    char* ws = (char*)d_ws;
    unsigned* h2  = (unsigned*)ws;                    // N*64 packed bf16x2
    float* a_src  = (float*)(h2 + (size_t)N * 64);    // N*4
    float* a_dst  = a_src + (size_t)N * 4;            // N*4
    int*   deg    = (int*)(a_dst + (size_t)N * 4);    // N
    int*   rowptr = deg + N;                          // N+1
    int*   cursor = rowptr + (N + 1) + 3;             // N  (16B-align)
    int*   csr    = cursor + N + 1;                   // E  (16B-align)
    int*   partial= csr + E;                          // NB
    int*   loc    = csr;   // alias: csr written only after loc consumed

    hipMemsetAsync(deg, 0, (size_t)N * sizeof(int), stream);

    k_gemm_att<<<512, 256, 0, stream>>>(x, Wg, att_src, att_dst, h2, a_src, a_dst, N);
    k_hist<<<2048, 256, 0, stream>>>(ei + E, deg, E);
    k_scan_local<<<NB, 256, 0, stream>>>(deg, loc, partial, N);
    k_scan_part<<<1, 64, 0, stream>>>(partial, rowptr + N, NB);
    k_scan_add<<<NB, 256, 0, stream>>>(loc, partial, rowptr, cursor, N);
    k_scatter<<<2048, 256, 0, stream>>>(ei, cursor, csr, E);
    k_agg<<<(N + 3) / 4, 256, 0, stream>>>(h2, a_src, a_dst, rowptr, csr,
                                           b_gat, W_lin, b_lin, out, N);
}

// Round 4
// 368.166 us; speedup vs baseline: 1.3058x; 1.3058x over previous
//
#include <hip/hip_runtime.h>

#define NSLOPE  0.2f

typedef __attribute__((ext_vector_type(8))) short bf16x8;
typedef __attribute__((ext_vector_type(4))) float f32x4;

__device__ __forceinline__ unsigned bf16_rne(float f) {
    unsigned x = __float_as_uint(f);
    return (x + 0x7fffu + ((x >> 16) & 1u)) >> 16;
}
__device__ __forceinline__ float bf_lo(unsigned u) { return __uint_as_float(u << 16); }
__device__ __forceinline__ float bf_hi(unsigned u) { return __uint_as_float(u & 0xffff0000u); }

// ---------------- Kernel 1: h2 = bf16(x @ W^T) via MFMA ----------------
// W (128x128) staged in LDS as bf16, row stride 136 (2-way bank alias = free).
// Each wave: 16 nodes x 128 out-channels = 8 D-tiles, K=128 in 4 mfma steps.
// Layouts (gfx950 16x16x32 bf16): A: row=l&15, k=(l>>4)*8+j; B: col=l&15,
// k=(l>>4)*8+j; D: col=l&15, row=(l>>4)*4+reg (m89-verified).
__global__ __launch_bounds__(256) void k_gemm(
    const float* __restrict__ x, const float* __restrict__ Wg,
    unsigned* __restrict__ h2, int N)
{
    __shared__ unsigned short Wl[128 * 136];   // bf16, rows=hc, cols=f

    const int t = threadIdx.x;
    const int wave = t >> 6, l = t & 63;

    // stage W as bf16 (16384 elems, 4 per thread-iter)
    for (int i = t; i < 128 * 32; i += 256) {
        int r = i >> 5, c4 = (i & 31) * 4;
        float4 w = *(const float4*)(Wg + r * 128 + c4);
        unsigned* wp = (unsigned*)((char*)Wl + r * 272 + c4 * 2);
        wp[0] = bf16_rne(w.x) | (bf16_rne(w.y) << 16);
        wp[1] = bf16_rne(w.z) | (bf16_rne(w.w) << 16);
    }
    __syncthreads();

    const int col = l & 15, kg = l >> 4;       // kg: k-group 0..3
    const int nwaves = gridDim.x * 4;
    const int wid = blockIdx.x * 4 + wave;

    for (int mb = wid * 16; mb < N; mb += nwaves * 16) {
        // ---- A fragments: 4 k-steps, 8 consecutive f each ----
        union { bf16x8 v; unsigned u[4]; } af[4];
        int row = mb + col; if (row >= N) row = N - 1;
        const float* xr = x + (size_t)row * 128 + kg * 8;
        #pragma unroll
        for (int s = 0; s < 4; ++s) {
            float4 xa = *(const float4*)(xr + s * 32);
            float4 xb = *(const float4*)(xr + s * 32 + 4);
            af[s].u[0] = bf16_rne(xa.x) | (bf16_rne(xa.y) << 16);
            af[s].u[1] = bf16_rne(xa.z) | (bf16_rne(xa.w) << 16);
            af[s].u[2] = bf16_rne(xb.x) | (bf16_rne(xb.y) << 16);
            af[s].u[3] = bf16_rne(xb.z) | (bf16_rne(xb.w) << 16);
        }

        f32x4 acc[8];
        #pragma unroll
        for (int tl = 0; tl < 8; ++tl) acc[tl] = (f32x4){0.f, 0.f, 0.f, 0.f};

        #pragma unroll
        for (int s = 0; s < 4; ++s) {
            #pragma unroll
            for (int tl = 0; tl < 8; ++tl) {
                const bf16x8 bf = *(const bf16x8*)((char*)Wl
                    + (tl * 16 + col) * 272 + (s * 32 + kg * 8) * 2);
                acc[tl] = __builtin_amdgcn_mfma_f32_16x16x32_bf16(af[s].v, bf, acc[tl], 0, 0, 0);
            }
        }

        // ---- pack channel pairs (c, c+64) and store ----
        #pragma unroll
        for (int tl = 0; tl < 4; ++tl) {
            #pragma unroll
            for (int r = 0; r < 4; ++r) {
                int node = mb + kg * 4 + r;
                if (node < N) {
                    unsigned w = bf16_rne(acc[tl][r]) | (bf16_rne(acc[tl + 4][r]) << 16);
                    h2[(size_t)node * 64 + tl * 16 + col] = w;
                }
            }
        }
    }
}

// ---------------- Kernel 1b: attention dots from h2 ----------------
__global__ __launch_bounds__(256) void k_att(
    const unsigned* __restrict__ h2, const float* __restrict__ att_src,
    const float* __restrict__ att_dst, float* __restrict__ a_src,
    float* __restrict__ a_dst, int N)
{
    const int t = threadIdx.x;
    const int wave = t >> 6, l = t & 63;
    const int n = blockIdx.x * 4 + wave;
    if (n >= N) return;

    unsigned u = h2[(size_t)n * 64 + l];
    float h0 = bf_lo(u), h1 = bf_hi(u);
    float ps = h0 * att_src[l],      pd = h0 * att_dst[l];       // heads l>>5 -> 0/1
    float qs = h1 * att_src[64 + l], qd = h1 * att_dst[64 + l];  // heads 2+(l>>5)
    #pragma unroll
    for (int m = 1; m < 32; m <<= 1) {
        ps += __shfl_xor(ps, m); pd += __shfl_xor(pd, m);
        qs += __shfl_xor(qs, m); qd += __shfl_xor(qd, m);
    }
    if (l == 0) {
        a_src[n * 4 + 0] = ps; a_dst[n * 4 + 0] = pd;
        a_src[n * 4 + 2] = qs; a_dst[n * 4 + 2] = qd;
    } else if (l == 32) {
        a_src[n * 4 + 1] = ps; a_dst[n * 4 + 1] = pd;
        a_src[n * 4 + 3] = qs; a_dst[n * 4 + 3] = qd;
    }
}

// ---------------- Kernel 2: in-degree histogram ----------------
__global__ void k_hist(const int* __restrict__ dst, int* __restrict__ deg, int E)
{
    int i = blockIdx.x * blockDim.x + threadIdx.x;
    int stride = gridDim.x * blockDim.x;
    for (; i < E; i += stride) atomicAdd(&deg[dst[i]], 1);
}

// ---------------- Kernel 3a: per-block local exclusive scan ----------------
__global__ __launch_bounds__(256) void k_scan_local(
    const int* __restrict__ deg, int* __restrict__ loc,
    int* __restrict__ partial, int N)
{
    __shared__ int wsum[4];
    const int t = threadIdx.x;
    const int base = blockIdx.x * 1024 + t * 4;

    int v0 = 0, v1 = 0, v2 = 0, v3 = 0;
    if (base + 3 < N) {
        int4 d = *(const int4*)(deg + base);
        v0 = d.x; v1 = d.y; v2 = d.z; v3 = d.w;
    } else if (base < N) {
        v0 = deg[base];
        if (base + 1 < N) v1 = deg[base + 1];
        if (base + 2 < N) v2 = deg[base + 2];
    }
    const int s = v0 + v1 + v2 + v3;

    const int l = t & 63;
    int sc = s;
    #pragma unroll
    for (int m = 1; m < 64; m <<= 1) {
        int u = __shfl_up(sc, m);
        if (l >= m) sc += u;
    }
    if (l == 63) wsum[t >> 6] = sc;
    __syncthreads();

    int woff = 0;
    const int w = t >> 6;
    #pragma unroll
    for (int i = 0; i < 4; ++i) if (i < w) woff += wsum[i];

    const int excl = woff + sc - s;
    if (base < N) {
        int o0 = excl, o1 = o0 + v0, o2 = o1 + v1, o3 = o2 + v2;
        if (base + 3 < N) {
            *(int4*)(loc + base) = make_int4(o0, o1, o2, o3);
        } else {
            loc[base] = o0;
            if (base + 1 < N) loc[base + 1] = o1;
            if (base + 2 < N) loc[base + 2] = o2;
        }
    }
    if (t == 255) partial[blockIdx.x] = woff + sc;
}

// ---------------- Kernel 3b: single-wave scan of block totals ----------------
__global__ __launch_bounds__(64) void k_scan_part(
    int* __restrict__ partial, int* __restrict__ total_out, int nb)
{
    const int l = threadIdx.x;
    int carry = 0;
    for (int base = 0; base < nb; base += 64) {
        int i = base + l;
        int v = (i < nb) ? partial[i] : 0;
        int sc = v;
        #pragma unroll
        for (int m = 1; m < 64; m <<= 1) {
            int u = __shfl_up(sc, m);
            if (l >= m) sc += u;
        }
        if (i < nb) partial[i] = carry + sc - v;
        carry += __shfl(sc, 63);
    }
    if (l == 0) *total_out = carry;
}

// ---------------- Kernel 3c: add block offsets ----------------
__global__ __launch_bounds__(256) void k_scan_add(
    const int* __restrict__ loc, const int* __restrict__ partial,
    int* __restrict__ rowptr, int* __restrict__ cursor, int N)
{
    const int off = partial[blockIdx.x];
    const int base = blockIdx.x * 1024 + threadIdx.x * 4;
    if (base + 3 < N) {
        int4 v = *(const int4*)(loc + base);
        v.x += off; v.y += off; v.z += off; v.w += off;
        *(int4*)(rowptr + base) = v;
        *(int4*)(cursor + base) = v;
    } else if (base < N) {
        for (int i = base; i < N && i < base + 4; ++i) {
            int v = loc[i] + off;
            rowptr[i] = v; cursor[i] = v;
        }
    }
}

// ---------------- Kernel 4: scatter src ids into CSR ----------------
__global__ void k_scatter(const int* __restrict__ ei, int* __restrict__ cursor,
                          int* __restrict__ csr, int E)
{
    int i = blockIdx.x * blockDim.x + threadIdx.x;
    int stride = gridDim.x * blockDim.x;
    for (; i < E; i += stride) {
        int s = ei[i];
        int d = ei[E + i];
        int pos = atomicAdd(&cursor[d], 1);
        csr[pos] = s;
    }
}

// ---------------- Kernel 4b: normalized alphas (exp once per edge-head) -----
// Wave per node. Lane = (edge slot e=l>>2, head hq=l&3). Raw exps kept in
// registers (deg<=64 fast path), normalized in-register, stored to alphaN in
// CSR order; self alpha stored per node.
__global__ __launch_bounds__(256) void k_alpha(
    const float* __restrict__ a_src, const float* __restrict__ a_dst,
    const int* __restrict__ rowptr, const int* __restrict__ csr,
    float* __restrict__ alphaN, float* __restrict__ selfa, int N)
{
    const int t = threadIdx.x;
    const int wave = t >> 6, l = t & 63;
    const int n = blockIdx.x * 4 + wave;
    if (n >= N) return;

    const int start = rowptr[n], end = rowptr[n + 1];
    const int deg = end - start;
    const int e = l >> 2, hq = l & 3;
    const float ad = a_dst[n * 4 + hq];

    // self exp (every lane, head hq)
    float evs = a_src[n * 4 + hq] + ad;
    evs = (evs >= 0.f) ? evs : NSLOPE * evs;
    const float psel = __expf(evs);

    if (deg <= 64) {
        float p0 = 0.f, p1 = 0.f, p2 = 0.f, p3 = 0.f;
        #define ALPHA_DO(c, pc)                                               \
            if (c * 16 < deg) {                                               \
                bool v = (c * 16 + e) < deg;                                  \
                int se = v ? csr[start + c * 16 + e] : 0;                     \
                float ev = a_src[se * 4 + hq] + ad;                           \
                ev = (ev >= 0.f) ? ev : NSLOPE * ev;                          \
                pc = v ? __expf(ev) : 0.f;                                    \
            }
        ALPHA_DO(0, p0) ALPHA_DO(1, p1) ALPHA_DO(2, p2) ALPHA_DO(3, p3)
        #undef ALPHA_DO
        float psum = p0 + p1 + p2 + p3;
        psum += __shfl_xor(psum, 4);
        psum += __shfl_xor(psum, 8);
        psum += __shfl_xor(psum, 16);
        psum += __shfl_xor(psum, 32);
        const float inv = 1.f / (psum + psel);
        #define ALPHA_ST(c, pc)                                               \
            if (c * 16 < deg && (c * 16 + e) < deg)                           \
                alphaN[(size_t)(start + c * 16 + e) * 4 + hq] = pc * inv;
        ALPHA_ST(0, p0) ALPHA_ST(1, p1) ALPHA_ST(2, p2) ALPHA_ST(3, p3)
        #undef ALPHA_ST
        if (e == 0) selfa[n * 4 + hq] = psel * inv;
    } else {
        // rare heavy node: recompute in second pass
        float psum = 0.f;
        for (int i = start + e; i < end; i += 16) {
            int se = csr[i];
            float ev = a_src[se * 4 + hq] + ad;
            ev = (ev >= 0.f) ? ev : NSLOPE * ev;
            psum += __expf(ev);
        }
        psum += __shfl_xor(psum, 4);
        psum += __shfl_xor(psum, 8);
        psum += __shfl_xor(psum, 16);
        psum += __shfl_xor(psum, 32);
        const float inv = 1.f / (psum + psel);
        for (int i = start + e; i < end; i += 16) {
            int se = csr[i];
            float ev = a_src[se * 4 + hq] + ad;
            ev = (ev >= 0.f) ? ev : NSLOPE * ev;
            alphaN[(size_t)i * 4 + hq] = __expf(ev) * inv;
        }
        if (e == 0) selfa[n * 4 + hq] = psel * inv;
    }
}

// ---------------- Kernel 5: weighted gather-sum + fused classifier ----------
// One wave per node. Pure gather loop: per 8-edge batch, 8 broadcast csr
// loads + 16 broadcast alpha loads + 8 independent h2 row gathers. No exp,
// no shuffles on the address path.
__global__ __launch_bounds__(256) void k_agg(
    const unsigned* __restrict__ h2, const float* __restrict__ alphaN,
    const float* __restrict__ selfa, const int* __restrict__ rowptr,
    const int* __restrict__ csr, const float* __restrict__ b_gat,
    const float* __restrict__ W_lin, const float* __restrict__ b_lin,
    float* __restrict__ out, int N)
{
    const int t = threadIdx.x;
    const int wave = t >> 6, l = t & 63;
    const int n = blockIdx.x * 4 + wave;
    if (n >= N) return;

    const int start = rowptr[n], end = rowptr[n + 1];
    const int hA = l >> 5, hB = 2 + hA;

    // self-loop contribution
    float acc0, acc1;
    {
        unsigned u = h2[(size_t)n * 64 + l];
        acc0 = selfa[n * 4 + hA] * bf_lo(u);
        acc1 = selfa[n * 4 + hB] * bf_hi(u);
    }

    int i = start;
    for (; i + 8 <= end; i += 8) {
        int sk[8]; float aA[8], aB[8]; unsigned u[8];
        #pragma unroll
        for (int k = 0; k < 8; ++k) sk[k] = csr[i + k];
        #pragma unroll
        for (int k = 0; k < 8; ++k) {
            aA[k] = alphaN[(size_t)(i + k) * 4 + hA];
            aB[k] = alphaN[(size_t)(i + k) * 4 + hB];
        }
        #pragma unroll
        for (int k = 0; k < 8; ++k) u[k] = h2[(size_t)sk[k] * 64 + l];
        #pragma unroll
        for (int k = 0; k < 8; ++k) {
            acc0 += aA[k] * bf_lo(u[k]);
            acc1 += aB[k] * bf_hi(u[k]);
        }
    }
    for (; i < end; ++i) {
        int s = csr[i];
        float aA = alphaN[(size_t)i * 4 + hA];
        float aB = alphaN[(size_t)i * 4 + hB];
        unsigned u = h2[(size_t)s * 64 + l];
        acc0 += aA * bf_lo(u);
        acc1 += aB * bf_hi(u);
    }

    // ---- fused epilogue: +b_gat, ReLU, Linear(128->2), wave reduce ----
    float r0 = fmaxf(acc0 + b_gat[l], 0.f);
    float r1 = fmaxf(acc1 + b_gat[64 + l], 0.f);
    float p0 = r0 * W_lin[l]       + r1 * W_lin[64 + l];
    float p1 = r0 * W_lin[128 + l] + r1 * W_lin[192 + l];
    #pragma unroll
    for (int m = 1; m < 64; m <<= 1) {
        p0 += __shfl_xor(p0, m);
        p1 += __shfl_xor(p1, m);
    }
    if (l == 0) {
        out[(size_t)n * 2]     = p0 + b_lin[0];
        out[(size_t)n * 2 + 1] = p1 + b_lin[1];
    }
}

// ---------------- launch ----------------
extern "C" void kernel_launch(void* const* d_in, const int* in_sizes, int n_in,
                              void* d_out, int out_size, void* d_ws, size_t ws_size,
                              hipStream_t stream)
{
    const float* x       = (const float*)d_in[0];
    const int*   ei      = (const int*)d_in[1];
    const float* Wg      = (const float*)d_in[2];
    const float* att_src = (const float*)d_in[3];
    const float* att_dst = (const float*)d_in[4];
    const float* b_gat   = (const float*)d_in[5];
    const float* W_lin   = (const float*)d_in[6];
    const float* b_lin   = (const float*)d_in[7];
    float* out = (float*)d_out;

    const int N = in_sizes[0] / 128;
    const int E = in_sizes[1] / 2;
    const int NB = (N + 1023) / 1024;

    // workspace layout
    char* ws = (char*)d_ws;
    unsigned* h2  = (unsigned*)ws;                    // N*64 packed bf16x2
    float* a_src  = (float*)(h2 + (size_t)N * 64);    // N*4
    float* a_dst  = a_src + (size_t)N * 4;            // N*4
    float* selfa  = a_dst + (size_t)N * 4;            // N*4
    int*   deg    = (int*)(selfa + (size_t)N * 4);    // N
    int*   rowptr = deg + N;                          // N+1
    int*   cursor = rowptr + (N + 1) + 3;             // N+1 (16B-align)
    int*   csr    = cursor + N + 1;                   // E
    float* alphaN = (float*)(csr + E);                // E*4
    int*   partial= (int*)(alphaN + (size_t)E * 4);   // NB
    int*   loc    = csr;   // alias: csr written only after loc consumed

    hipMemsetAsync(deg, 0, (size_t)N * sizeof(int), stream);

    k_gemm<<<512, 256, 0, stream>>>(x, Wg, h2, N);
    k_att<<<(N + 3) / 4, 256, 0, stream>>>(h2, att_src, att_dst, a_src, a_dst, N);
    k_hist<<<2048, 256, 0, stream>>>(ei + E, deg, E);
    k_scan_local<<<NB, 256, 0, stream>>>(deg, loc, partial, N);
    k_scan_part<<<1, 64, 0, stream>>>(partial, rowptr + N, NB);
    k_scan_add<<<NB, 256, 0, stream>>>(loc, partial, rowptr, cursor, N);
    k_scatter<<<2048, 256, 0, stream>>>(ei, cursor, csr, E);
    k_alpha<<<(N + 3) / 4, 256, 0, stream>>>(a_src, a_dst, rowptr, csr, alphaN, selfa, N);
    k_agg<<<(N + 3) / 4, 256, 0, stream>>>(h2, alphaN, selfa, rowptr, csr,
                                           b_gat, W_lin, b_lin, out, N);
}

// Round 5
// 278.898 us; speedup vs baseline: 1.7238x; 1.3201x over previous
//
#include <hip/hip_runtime.h>

#define NSLOPE  0.2f

typedef __attribute__((ext_vector_type(8))) short bf16x8;
typedef __attribute__((ext_vector_type(4))) float f32x4;

__device__ __forceinline__ unsigned bf16_rne(float f) {
    unsigned x = __float_as_uint(f);
    return (x + 0x7fffu + ((x >> 16) & 1u)) >> 16;
}
__device__ __forceinline__ float bf_lo(unsigned u) { return __uint_as_float(u << 16); }
__device__ __forceinline__ float bf_hi(unsigned u) { return __uint_as_float(u & 0xffff0000u); }

// ---------------- Kernel 1: h2 = bf16(x @ W^T) via MFMA ----------------
__global__ __launch_bounds__(256) void k_gemm(
    const float* __restrict__ x, const float* __restrict__ Wg,
    unsigned* __restrict__ h2, int N)
{
    __shared__ unsigned short Wl[128 * 136];   // bf16, rows=hc, cols=f

    const int t = threadIdx.x;
    const int wave = t >> 6, l = t & 63;

    for (int i = t; i < 128 * 32; i += 256) {
        int r = i >> 5, c4 = (i & 31) * 4;
        float4 w = *(const float4*)(Wg + r * 128 + c4);
        unsigned* wp = (unsigned*)((char*)Wl + r * 272 + c4 * 2);
        wp[0] = bf16_rne(w.x) | (bf16_rne(w.y) << 16);
        wp[1] = bf16_rne(w.z) | (bf16_rne(w.w) << 16);
    }
    __syncthreads();

    const int col = l & 15, kg = l >> 4;
    const int nwaves = gridDim.x * 4;
    const int wid = blockIdx.x * 4 + wave;

    for (int mb = wid * 16; mb < N; mb += nwaves * 16) {
        union { bf16x8 v; unsigned u[4]; } af[4];
        int row = mb + col; if (row >= N) row = N - 1;
        const float* xr = x + (size_t)row * 128 + kg * 8;
        #pragma unroll
        for (int s = 0; s < 4; ++s) {
            float4 xa = *(const float4*)(xr + s * 32);
            float4 xb = *(const float4*)(xr + s * 32 + 4);
            af[s].u[0] = bf16_rne(xa.x) | (bf16_rne(xa.y) << 16);
            af[s].u[1] = bf16_rne(xa.z) | (bf16_rne(xa.w) << 16);
            af[s].u[2] = bf16_rne(xb.x) | (bf16_rne(xb.y) << 16);
            af[s].u[3] = bf16_rne(xb.z) | (bf16_rne(xb.w) << 16);
        }

        f32x4 acc[8];
        #pragma unroll
        for (int tl = 0; tl < 8; ++tl) acc[tl] = (f32x4){0.f, 0.f, 0.f, 0.f};

        #pragma unroll
        for (int s = 0; s < 4; ++s) {
            #pragma unroll
            for (int tl = 0; tl < 8; ++tl) {
                const bf16x8 bf = *(const bf16x8*)((char*)Wl
                    + (tl * 16 + col) * 272 + (s * 32 + kg * 8) * 2);
                acc[tl] = __builtin_amdgcn_mfma_f32_16x16x32_bf16(af[s].v, bf, acc[tl], 0, 0, 0);
            }
        }

        #pragma unroll
        for (int tl = 0; tl < 4; ++tl) {
            #pragma unroll
            for (int r = 0; r < 4; ++r) {
                int node = mb + kg * 4 + r;
                if (node < N) {
                    unsigned w = bf16_rne(acc[tl][r]) | (bf16_rne(acc[tl + 4][r]) << 16);
                    h2[(size_t)node * 64 + tl * 16 + col] = w;
                }
            }
        }
    }
}

// ---------------- Kernel 1b: attention dots from h2 ----------------
__global__ __launch_bounds__(256) void k_att(
    const unsigned* __restrict__ h2, const float* __restrict__ att_src,
    const float* __restrict__ att_dst, float* __restrict__ a_src,
    float* __restrict__ a_dst, int N)
{
    const int t = threadIdx.x;
    const int wave = t >> 6, l = t & 63;
    const int n = blockIdx.x * 4 + wave;
    if (n >= N) return;

    unsigned u = h2[(size_t)n * 64 + l];
    float h0 = bf_lo(u), h1 = bf_hi(u);
    float ps = h0 * att_src[l],      pd = h0 * att_dst[l];
    float qs = h1 * att_src[64 + l], qd = h1 * att_dst[64 + l];
    #pragma unroll
    for (int m = 1; m < 32; m <<= 1) {
        ps += __shfl_xor(ps, m); pd += __shfl_xor(pd, m);
        qs += __shfl_xor(qs, m); qd += __shfl_xor(qd, m);
    }
    if (l == 0) {
        a_src[n * 4 + 0] = ps; a_dst[n * 4 + 0] = pd;
        a_src[n * 4 + 2] = qs; a_dst[n * 4 + 2] = qd;
    } else if (l == 32) {
        a_src[n * 4 + 1] = ps; a_dst[n * 4 + 1] = pd;
        a_src[n * 4 + 3] = qs; a_dst[n * 4 + 3] = qd;
    }
}

// ---------------- Kernel 2: in-degree histogram ----------------
__global__ void k_hist(const int* __restrict__ dst, int* __restrict__ deg, int E)
{
    int i = blockIdx.x * blockDim.x + threadIdx.x;
    int stride = gridDim.x * blockDim.x;
    for (; i < E; i += stride) atomicAdd(&deg[dst[i]], 1);
}

// ---------------- Kernel 3a: per-block local exclusive scan ----------------
__global__ __launch_bounds__(256) void k_scan_local(
    const int* __restrict__ deg, int* __restrict__ loc,
    int* __restrict__ partial, int N)
{
    __shared__ int wsum[4];
    const int t = threadIdx.x;
    const int base = blockIdx.x * 1024 + t * 4;

    int v0 = 0, v1 = 0, v2 = 0, v3 = 0;
    if (base + 3 < N) {
        int4 d = *(const int4*)(deg + base);
        v0 = d.x; v1 = d.y; v2 = d.z; v3 = d.w;
    } else if (base < N) {
        v0 = deg[base];
        if (base + 1 < N) v1 = deg[base + 1];
        if (base + 2 < N) v2 = deg[base + 2];
    }
    const int s = v0 + v1 + v2 + v3;

    const int l = t & 63;
    int sc = s;
    #pragma unroll
    for (int m = 1; m < 64; m <<= 1) {
        int u = __shfl_up(sc, m);
        if (l >= m) sc += u;
    }
    if (l == 63) wsum[t >> 6] = sc;
    __syncthreads();

    int woff = 0;
    const int w = t >> 6;
    #pragma unroll
    for (int i = 0; i < 4; ++i) if (i < w) woff += wsum[i];

    const int excl = woff + sc - s;
    if (base < N) {
        int o0 = excl, o1 = o0 + v0, o2 = o1 + v1, o3 = o2 + v2;
        if (base + 3 < N) {
            *(int4*)(loc + base) = make_int4(o0, o1, o2, o3);
        } else {
            loc[base] = o0;
            if (base + 1 < N) loc[base + 1] = o1;
            if (base + 2 < N) loc[base + 2] = o2;
        }
    }
    if (t == 255) partial[blockIdx.x] = woff + sc;
}

// ---------------- Kernel 3b: single-wave scan (also reused for bucket bases)
__global__ __launch_bounds__(64) void k_scan_part(
    int* __restrict__ partial, int* __restrict__ total_out, int nb)
{
    const int l = threadIdx.x;
    int carry = 0;
    for (int base = 0; base < nb; base += 64) {
        int i = base + l;
        int v = (i < nb) ? partial[i] : 0;
        int sc = v;
        #pragma unroll
        for (int m = 1; m < 64; m <<= 1) {
            int u = __shfl_up(sc, m);
            if (l >= m) sc += u;
        }
        if (i < nb) partial[i] = carry + sc - v;
        carry += __shfl(sc, 63);
    }
    if (l == 0) *total_out = carry;
}

// ---------------- Kernel 3c: add block offsets -> rowptr ----------------
__global__ __launch_bounds__(256) void k_scan_add(
    const int* __restrict__ loc, const int* __restrict__ partial,
    int* __restrict__ rowptr, int N)
{
    const int off = partial[blockIdx.x];
    const int base = blockIdx.x * 1024 + threadIdx.x * 4;
    if (base + 3 < N) {
        int4 v = *(const int4*)(loc + base);
        v.x += off; v.y += off; v.z += off; v.w += off;
        *(int4*)(rowptr + base) = v;
    } else if (base < N) {
        for (int i = base; i < N && i < base + 4; ++i)
            rowptr[i] = loc[i] + off;
    }
}

// ---------------- CSR build: two-level counting sort ----------------
// Pass A: per-block histogram of dst>>7 -> M[bucket][block]
__global__ __launch_bounds__(256) void k_partA(
    const int* __restrict__ dst, int* __restrict__ M,
    int E, int nbkt, int chunk)
{
    __shared__ int hist[1024];
    for (int i = threadIdx.x; i < nbkt; i += 256) hist[i] = 0;
    __syncthreads();
    const int lo = blockIdx.x * chunk, hi = min(lo + chunk, E);
    for (int e = lo + threadIdx.x; e < hi; e += 256)
        atomicAdd(&hist[dst[e] >> 7], 1);
    __syncthreads();
    for (int i = threadIdx.x; i < nbkt; i += 256)
        M[(size_t)i * gridDim.x + blockIdx.x] = hist[i];
}

// Pass A2: one wave per bucket: exclusive scan of M row, total -> bb[b]
__global__ __launch_bounds__(64) void k_bscan(
    int* __restrict__ M, int* __restrict__ bb, int nblk)
{
    const int l = threadIdx.x;
    int* row = M + (size_t)blockIdx.x * nblk;
    int carry = 0;
    for (int base = 0; base < nblk; base += 64) {
        int i = base + l;
        int v = (i < nblk) ? row[i] : 0;
        int sc = v;
        #pragma unroll
        for (int m = 1; m < 64; m <<= 1) {
            int u = __shfl_up(sc, m);
            if (l >= m) sc += u;
        }
        if (i < nblk) row[i] = carry + sc - v;
        carry += __shfl(sc, 63);
    }
    if (l == 0) bb[blockIdx.x] = carry;
}

// Pass B: stable scatter into bucket-contiguous staging (packed src|dlow<<25)
__global__ __launch_bounds__(256) void k_partB(
    const int* __restrict__ ei, const int* __restrict__ M,
    const int* __restrict__ bb, unsigned* __restrict__ stage,
    int E, int nbkt, int chunk)
{
    __shared__ int cur[1024];
    const int blk = blockIdx.x, nblk = gridDim.x;
    for (int i = threadIdx.x; i < nbkt; i += 256)
        cur[i] = M[(size_t)i * nblk + blk] + bb[i];
    __syncthreads();
    const int lo = blk * chunk, hi = min(lo + chunk, E);
    for (int e = lo + threadIdx.x; e < hi; e += 256) {
        int s = ei[e];
        int d = ei[E + e];
        int pos = atomicAdd(&cur[d >> 7], 1);
        stage[pos] = (unsigned)s | ((unsigned)(d & 127) << 25);
    }
}

// Pass C: one block per bucket; LDS cursors from rowptr; csr writes land in
// an ~8KB contiguous window (L2-absorbed).
__global__ __launch_bounds__(256) void k_partC(
    const unsigned* __restrict__ stage, const int* __restrict__ bb,
    const int* __restrict__ rowptr, int* __restrict__ csr, int N)
{
    __shared__ int cur[128];
    const int b = blockIdx.x, t = threadIdx.x;
    if (t < 128) {
        int n = (b << 7) + t;
        cur[t] = (n < N) ? rowptr[n] : 0;
    }
    __syncthreads();
    const int lo = bb[b], hi = bb[b + 1];
    for (int e = lo + t; e < hi; e += 256) {
        unsigned u = stage[e];
        int s = (int)(u & 0x1FFFFFFu);
        int dl = (int)(u >> 25);
        int pos = atomicAdd(&cur[dl], 1);
        csr[pos] = s;
    }
}

// ---------------- Kernel 4b: normalized alphas ----------------
__global__ __launch_bounds__(256) void k_alpha(
    const float* __restrict__ a_src, const float* __restrict__ a_dst,
    const int* __restrict__ rowptr, const int* __restrict__ csr,
    float* __restrict__ alphaN, float* __restrict__ selfa, int N)
{
    const int t = threadIdx.x;
    const int wave = t >> 6, l = t & 63;
    const int n = blockIdx.x * 4 + wave;
    if (n >= N) return;

    const int start = rowptr[n], end = rowptr[n + 1];
    const int deg = end - start;
    const int e = l >> 2, hq = l & 3;
    const float ad = a_dst[n * 4 + hq];

    float evs = a_src[n * 4 + hq] + ad;
    evs = (evs >= 0.f) ? evs : NSLOPE * evs;
    const float psel = __expf(evs);

    if (deg <= 64) {
        float p0 = 0.f, p1 = 0.f, p2 = 0.f, p3 = 0.f;
        #define ALPHA_DO(c, pc)                                               \
            if (c * 16 < deg) {                                               \
                bool v = (c * 16 + e) < deg;                                  \
                int se = v ? csr[start + c * 16 + e] : 0;                     \
                float ev = a_src[se * 4 + hq] + ad;                           \
                ev = (ev >= 0.f) ? ev : NSLOPE * ev;                          \
                pc = v ? __expf(ev) : 0.f;                                    \
            }
        ALPHA_DO(0, p0) ALPHA_DO(1, p1) ALPHA_DO(2, p2) ALPHA_DO(3, p3)
        #undef ALPHA_DO
        float psum = p0 + p1 + p2 + p3;
        psum += __shfl_xor(psum, 4);
        psum += __shfl_xor(psum, 8);
        psum += __shfl_xor(psum, 16);
        psum += __shfl_xor(psum, 32);
        const float inv = 1.f / (psum + psel);
        #define ALPHA_ST(c, pc)                                               \
            if (c * 16 < deg && (c * 16 + e) < deg)                           \
                alphaN[(size_t)(start + c * 16 + e) * 4 + hq] = pc * inv;
        ALPHA_ST(0, p0) ALPHA_ST(1, p1) ALPHA_ST(2, p2) ALPHA_ST(3, p3)
        #undef ALPHA_ST
        if (e == 0) selfa[n * 4 + hq] = psel * inv;
    } else {
        float psum = 0.f;
        for (int i = start + e; i < end; i += 16) {
            int se = csr[i];
            float ev = a_src[se * 4 + hq] + ad;
            ev = (ev >= 0.f) ? ev : NSLOPE * ev;
            psum += __expf(ev);
        }
        psum += __shfl_xor(psum, 4);
        psum += __shfl_xor(psum, 8);
        psum += __shfl_xor(psum, 16);
        psum += __shfl_xor(psum, 32);
        const float inv = 1.f / (psum + psel);
        for (int i = start + e; i < end; i += 16) {
            int se = csr[i];
            float ev = a_src[se * 4 + hq] + ad;
            ev = (ev >= 0.f) ? ev : NSLOPE * ev;
            alphaN[(size_t)i * 4 + hq] = __expf(ev) * inv;
        }
        if (e == 0) selfa[n * 4 + hq] = psel * inv;
    }
}

// ---------------- Kernel 5: weighted gather-sum + fused classifier ----------
__global__ __launch_bounds__(256) void k_agg(
    const unsigned* __restrict__ h2, const float* __restrict__ alphaN,
    const float* __restrict__ selfa, const int* __restrict__ rowptr,
    const int* __restrict__ csr, const float* __restrict__ b_gat,
    const float* __restrict__ W_lin, const float* __restrict__ b_lin,
    float* __restrict__ out, int N)
{
    const int t = threadIdx.x;
    const int wave = t >> 6, l = t & 63;
    const int n = blockIdx.x * 4 + wave;
    if (n >= N) return;

    const int start = rowptr[n], end = rowptr[n + 1];
    const int hA = l >> 5, hB = 2 + hA;

    float acc0, acc1;
    {
        unsigned u = h2[(size_t)n * 64 + l];
        acc0 = selfa[n * 4 + hA] * bf_lo(u);
        acc1 = selfa[n * 4 + hB] * bf_hi(u);
    }

    int i = start;
    for (; i + 8 <= end; i += 8) {
        int sk[8]; float aA[8], aB[8]; unsigned u[8];
        #pragma unroll
        for (int k = 0; k < 8; ++k) sk[k] = csr[i + k];
        #pragma unroll
        for (int k = 0; k < 8; ++k) {
            aA[k] = alphaN[(size_t)(i + k) * 4 + hA];
            aB[k] = alphaN[(size_t)(i + k) * 4 + hB];
        }
        #pragma unroll
        for (int k = 0; k < 8; ++k) u[k] = h2[(size_t)sk[k] * 64 + l];
        #pragma unroll
        for (int k = 0; k < 8; ++k) {
            acc0 += aA[k] * bf_lo(u[k]);
            acc1 += aB[k] * bf_hi(u[k]);
        }
    }
    for (; i < end; ++i) {
        int s = csr[i];
        float aA = alphaN[(size_t)i * 4 + hA];
        float aB = alphaN[(size_t)i * 4 + hB];
        unsigned u = h2[(size_t)s * 64 + l];
        acc0 += aA * bf_lo(u);
        acc1 += aB * bf_hi(u);
    }

    float r0 = fmaxf(acc0 + b_gat[l], 0.f);
    float r1 = fmaxf(acc1 + b_gat[64 + l], 0.f);
    float p0 = r0 * W_lin[l]       + r1 * W_lin[64 + l];
    float p1 = r0 * W_lin[128 + l] + r1 * W_lin[192 + l];
    #pragma unroll
    for (int m = 1; m < 64; m <<= 1) {
        p0 += __shfl_xor(p0, m);
        p1 += __shfl_xor(p1, m);
    }
    if (l == 0) {
        out[(size_t)n * 2]     = p0 + b_lin[0];
        out[(size_t)n * 2 + 1] = p1 + b_lin[1];
    }
}

// ---------------- launch ----------------
extern "C" void kernel_launch(void* const* d_in, const int* in_sizes, int n_in,
                              void* d_out, int out_size, void* d_ws, size_t ws_size,
                              hipStream_t stream)
{
    const float* x       = (const float*)d_in[0];
    const int*   ei      = (const int*)d_in[1];
    const float* Wg      = (const float*)d_in[2];
    const float* att_src = (const float*)d_in[3];
    const float* att_dst = (const float*)d_in[4];
    const float* b_gat   = (const float*)d_in[5];
    const float* W_lin   = (const float*)d_in[6];
    const float* b_lin   = (const float*)d_in[7];
    float* out = (float*)d_out;

    const int N = in_sizes[0] / 128;
    const int E = in_sizes[1] / 2;
    const int NB = (N + 1023) / 1024;          // scan blocks
    const int NBKT = (N + 127) >> 7;           // partition buckets (<=1024)
    const int NBLKA = 256;                     // partition blocks
    const int CHUNK = (E + NBLKA - 1) / NBLKA;

    // workspace layout
    char* ws = (char*)d_ws;
    unsigned* h2  = (unsigned*)ws;                    // N*64 packed bf16x2
    float* a_src  = (float*)(h2 + (size_t)N * 64);    // N*4
    float* a_dst  = a_src + (size_t)N * 4;            // N*4
    float* selfa  = a_dst + (size_t)N * 4;            // N*4
    int*   deg    = (int*)(selfa + (size_t)N * 4);    // N
    int*   rowptr = deg + N;                          // N+1
    int*   csr    = rowptr + (N + 1) + 3;             // E  (16B-align)
    float* alphaN = (float*)(csr + E);                // E*4
    int*   partial= (int*)(alphaN + (size_t)E * 4);   // NB
    int*   M      = partial + NB;                     // NBKT*NBLKA
    int*   bb     = M + (size_t)NBKT * NBLKA;         // NBKT+1
    int*   loc    = csr;                              // alias (csr written later)
    unsigned* stage = (unsigned*)alphaN;              // alias (dead before k_alpha)

    hipMemsetAsync(deg, 0, (size_t)N * sizeof(int), stream);

    k_gemm<<<512, 256, 0, stream>>>(x, Wg, h2, N);
    k_att<<<(N + 3) / 4, 256, 0, stream>>>(h2, att_src, att_dst, a_src, a_dst, N);
    k_hist<<<2048, 256, 0, stream>>>(ei + E, deg, E);
    k_scan_local<<<NB, 256, 0, stream>>>(deg, loc, partial, N);
    k_scan_part<<<1, 64, 0, stream>>>(partial, rowptr + N, NB);
    k_scan_add<<<NB, 256, 0, stream>>>(loc, partial, rowptr, N);
    k_partA<<<NBLKA, 256, 0, stream>>>(ei + E, M, E, NBKT, CHUNK);
    k_bscan<<<NBKT, 64, 0, stream>>>(M, bb, NBLKA);
    k_scan_part<<<1, 64, 0, stream>>>(bb, bb + NBKT, NBKT);
    k_partB<<<NBLKA, 256, 0, stream>>>(ei, M, bb, stage, E, NBKT, CHUNK);
    k_partC<<<NBKT, 256, 0, stream>>>(stage, bb, rowptr, csr, N);
    k_alpha<<<(N + 3) / 4, 256, 0, stream>>>(a_src, a_dst, rowptr, csr, alphaN, selfa, N);
    k_agg<<<(N + 3) / 4, 256, 0, stream>>>(h2, alphaN, selfa, rowptr, csr,
                                           b_gat, W_lin, b_lin, out, N);
}

// Round 6
// 221.768 us; speedup vs baseline: 2.1678x; 1.2576x over previous
//
#include <hip/hip_runtime.h>

#define NSLOPE  0.2f

typedef __attribute__((ext_vector_type(8))) short bf16x8;
typedef __attribute__((ext_vector_type(4))) float f32x4;

__device__ __forceinline__ unsigned bf16_rne(float f) {
    unsigned x = __float_as_uint(f);
    return (x + 0x7fffu + ((x >> 16) & 1u)) >> 16;
}
__device__ __forceinline__ float bf_lo(unsigned u) { return __uint_as_float(u << 16); }
__device__ __forceinline__ float bf_hi(unsigned u) { return __uint_as_float(u & 0xffff0000u); }

// ---------------- Kernel 1: h2 = bf16(x @ W^T) via MFMA ----------------
__global__ __launch_bounds__(256) void k_gemm(
    const float* __restrict__ x, const float* __restrict__ Wg,
    unsigned* __restrict__ h2, int N)
{
    __shared__ unsigned short Wl[128 * 136];   // bf16, rows=hc, cols=f

    const int t = threadIdx.x;
    const int wave = t >> 6, l = t & 63;

    for (int i = t; i < 128 * 32; i += 256) {
        int r = i >> 5, c4 = (i & 31) * 4;
        float4 w = *(const float4*)(Wg + r * 128 + c4);
        unsigned* wp = (unsigned*)((char*)Wl + r * 272 + c4 * 2);
        wp[0] = bf16_rne(w.x) | (bf16_rne(w.y) << 16);
        wp[1] = bf16_rne(w.z) | (bf16_rne(w.w) << 16);
    }
    __syncthreads();

    const int col = l & 15, kg = l >> 4;
    const int nwaves = gridDim.x * 4;
    const int wid = blockIdx.x * 4 + wave;

    for (int mb = wid * 16; mb < N; mb += nwaves * 16) {
        union { bf16x8 v; unsigned u[4]; } af[4];
        int row = mb + col; if (row >= N) row = N - 1;
        const float* xr = x + (size_t)row * 128 + kg * 8;
        #pragma unroll
        for (int s = 0; s < 4; ++s) {
            float4 xa = *(const float4*)(xr + s * 32);
            float4 xb = *(const float4*)(xr + s * 32 + 4);
            af[s].u[0] = bf16_rne(xa.x) | (bf16_rne(xa.y) << 16);
            af[s].u[1] = bf16_rne(xa.z) | (bf16_rne(xa.w) << 16);
            af[s].u[2] = bf16_rne(xb.x) | (bf16_rne(xb.y) << 16);
            af[s].u[3] = bf16_rne(xb.z) | (bf16_rne(xb.w) << 16);
        }

        f32x4 acc[8];
        #pragma unroll
        for (int tl = 0; tl < 8; ++tl) acc[tl] = (f32x4){0.f, 0.f, 0.f, 0.f};

        #pragma unroll
        for (int s = 0; s < 4; ++s) {
            #pragma unroll
            for (int tl = 0; tl < 8; ++tl) {
                const bf16x8 bf = *(const bf16x8*)((char*)Wl
                    + (tl * 16 + col) * 272 + (s * 32 + kg * 8) * 2);
                acc[tl] = __builtin_amdgcn_mfma_f32_16x16x32_bf16(af[s].v, bf, acc[tl], 0, 0, 0);
            }
        }

        #pragma unroll
        for (int tl = 0; tl < 4; ++tl) {
            #pragma unroll
            for (int r = 0; r < 4; ++r) {
                int node = mb + kg * 4 + r;
                if (node < N) {
                    unsigned w = bf16_rne(acc[tl][r]) | (bf16_rne(acc[tl + 4][r]) << 16);
                    h2[(size_t)node * 64 + tl * 16 + col] = w;
                }
            }
        }
    }
}

// ---------------- Kernel 1b: attention dots from h2 ----------------
__global__ __launch_bounds__(256) void k_att(
    const unsigned* __restrict__ h2, const float* __restrict__ att_src,
    const float* __restrict__ att_dst, float* __restrict__ a_src,
    float* __restrict__ a_dst, int N)
{
    const int t = threadIdx.x;
    const int wave = t >> 6, l = t & 63;
    const int n = blockIdx.x * 4 + wave;
    if (n >= N) return;

    unsigned u = h2[(size_t)n * 64 + l];
    float h0 = bf_lo(u), h1 = bf_hi(u);
    float ps = h0 * att_src[l],      pd = h0 * att_dst[l];
    float qs = h1 * att_src[64 + l], qd = h1 * att_dst[64 + l];
    #pragma unroll
    for (int m = 1; m < 32; m <<= 1) {
        ps += __shfl_xor(ps, m); pd += __shfl_xor(pd, m);
        qs += __shfl_xor(qs, m); qd += __shfl_xor(qd, m);
    }
    if (l == 0) {
        a_src[n * 4 + 0] = ps; a_dst[n * 4 + 0] = pd;
        a_src[n * 4 + 2] = qs; a_dst[n * 4 + 2] = qd;
    } else if (l == 32) {
        a_src[n * 4 + 1] = ps; a_dst[n * 4 + 1] = pd;
        a_src[n * 4 + 3] = qs; a_dst[n * 4 + 3] = qd;
    }
}

// ---------------- single-wave exclusive scan (bucket bases) ----------------
__global__ __launch_bounds__(64) void k_scan_part(
    int* __restrict__ partial, int* __restrict__ total_out, int nb)
{
    const int l = threadIdx.x;
    int carry = 0;
    for (int base = 0; base < nb; base += 64) {
        int i = base + l;
        int v = (i < nb) ? partial[i] : 0;
        int sc = v;
        #pragma unroll
        for (int m = 1; m < 64; m <<= 1) {
            int u = __shfl_up(sc, m);
            if (l >= m) sc += u;
        }
        if (i < nb) partial[i] = carry + sc - v;
        carry += __shfl(sc, 63);
    }
    if (l == 0) *total_out = carry;
}

// ---------------- CSR build: two-level counting sort ----------------
// Pass A: per-block histogram of dst>>7 -> M[bucket][block]
__global__ __launch_bounds__(256) void k_partA(
    const int* __restrict__ dst, int* __restrict__ M,
    int E, int nbkt, int chunk)
{
    __shared__ int hist[1024];
    for (int i = threadIdx.x; i < nbkt; i += 256) hist[i] = 0;
    __syncthreads();
    const int lo = blockIdx.x * chunk, hi = min(lo + chunk, E);
    for (int e = lo + threadIdx.x; e < hi; e += 256)
        atomicAdd(&hist[dst[e] >> 7], 1);
    __syncthreads();
    for (int i = threadIdx.x; i < nbkt; i += 256)
        M[(size_t)i * gridDim.x + blockIdx.x] = hist[i];
}

// Pass A2: one wave per bucket: exclusive scan of M row, total -> bb[b]
__global__ __launch_bounds__(64) void k_bscan(
    int* __restrict__ M, int* __restrict__ bb, int nblk)
{
    const int l = threadIdx.x;
    int* row = M + (size_t)blockIdx.x * nblk;
    int carry = 0;
    for (int base = 0; base < nblk; base += 64) {
        int i = base + l;
        int v = (i < nblk) ? row[i] : 0;
        int sc = v;
        #pragma unroll
        for (int m = 1; m < 64; m <<= 1) {
            int u = __shfl_up(sc, m);
            if (l >= m) sc += u;
        }
        if (i < nblk) row[i] = carry + sc - v;
        carry += __shfl(sc, 63);
    }
    if (l == 0) bb[blockIdx.x] = carry;
}

// Pass B: stable scatter into bucket-contiguous staging (packed src|dlow<<25)
__global__ __launch_bounds__(256) void k_partB(
    const int* __restrict__ ei, const int* __restrict__ M,
    const int* __restrict__ bb, unsigned* __restrict__ stage,
    int E, int nbkt, int chunk)
{
    __shared__ int cur[1024];
    const int blk = blockIdx.x, nblk = gridDim.x;
    for (int i = threadIdx.x; i < nbkt; i += 256)
        cur[i] = M[(size_t)i * nblk + blk] + bb[i];
    __syncthreads();
    const int lo = blk * chunk, hi = min(lo + chunk, E);
    for (int e = lo + threadIdx.x; e < hi; e += 256) {
        int s = ei[e];
        int d = ei[E + e];
        int pos = atomicAdd(&cur[d >> 7], 1);
        stage[pos] = (unsigned)s | ((unsigned)(d & 127) << 25);
    }
}

// Pass C: one block per bucket. Derives rowptr (LDS count + 128-scan + bb[b])
// then sorts the bucket's staged edges into csr (writes in ~8KB L2 window).
__global__ __launch_bounds__(256) void k_partC(
    const unsigned* __restrict__ stage, const int* __restrict__ bb,
    int* __restrict__ rowptr, int* __restrict__ csr, int N, int E)
{
    __shared__ int cnt[128];
    __shared__ int cur[128];
    __shared__ int wtot;
    const int b = blockIdx.x, t = threadIdx.x;
    if (t < 128) cnt[t] = 0;
    __syncthreads();
    const int lo = bb[b], hi = bb[b + 1];
    for (int e = lo + t; e < hi; e += 256)
        atomicAdd(&cnt[stage[e] >> 25], 1);
    __syncthreads();
    // 128-entry exclusive scan with 2 waves
    int v = 0, sc = 0;
    const int l = t & 63;
    if (t < 128) {
        v = cnt[t];
        sc = v;
        #pragma unroll
        for (int m = 1; m < 64; m <<= 1) {
            int u = __shfl_up(sc, m);
            if (l >= m) sc += u;
        }
        if (t == 63) wtot = sc;
    }
    __syncthreads();
    if (t < 128) {
        int c = lo + sc - v + ((t >= 64) ? wtot : 0);
        cur[t] = c;
        int n = (b << 7) + t;
        if (n < N) rowptr[n] = c;
    }
    if (t == 0 && b == gridDim.x - 1) rowptr[N] = E;
    __syncthreads();
    for (int e = lo + t; e < hi; e += 256) {
        unsigned u = stage[e];
        int pos = atomicAdd(&cur[u >> 25], 1);
        csr[pos] = (int)(u & 0x1FFFFFFu);
    }
}

// ---------------- Kernel 4b: normalized alphas (bf16-packed) ----------------
__global__ __launch_bounds__(256) void k_alpha(
    const float* __restrict__ a_src, const float* __restrict__ a_dst,
    const int* __restrict__ rowptr, const int* __restrict__ csr,
    unsigned short* __restrict__ alphaH, float* __restrict__ selfa, int N)
{
    const int t = threadIdx.x;
    const int wave = t >> 6, l = t & 63;
    const int n = blockIdx.x * 4 + wave;
    if (n >= N) return;

    const int start = rowptr[n], end = rowptr[n + 1];
    const int deg = end - start;
    const int e = l >> 2, hq = l & 3;
    const float ad = a_dst[n * 4 + hq];

    float evs = a_src[n * 4 + hq] + ad;
    evs = (evs >= 0.f) ? evs : NSLOPE * evs;
    const float psel = __expf(evs);

    if (deg <= 64) {
        float p0 = 0.f, p1 = 0.f, p2 = 0.f, p3 = 0.f;
        #define ALPHA_DO(c, pc)                                               \
            if (c * 16 < deg) {                                               \
                bool vv = (c * 16 + e) < deg;                                 \
                int se = vv ? csr[start + c * 16 + e] : 0;                    \
                float ev = a_src[se * 4 + hq] + ad;                           \
                ev = (ev >= 0.f) ? ev : NSLOPE * ev;                          \
                pc = vv ? __expf(ev) : 0.f;                                   \
            }
        ALPHA_DO(0, p0) ALPHA_DO(1, p1) ALPHA_DO(2, p2) ALPHA_DO(3, p3)
        #undef ALPHA_DO
        float psum = p0 + p1 + p2 + p3;
        psum += __shfl_xor(psum, 4);
        psum += __shfl_xor(psum, 8);
        psum += __shfl_xor(psum, 16);
        psum += __shfl_xor(psum, 32);
        const float inv = 1.f / (psum + psel);
        #define ALPHA_ST(c, pc)                                               \
            if (c * 16 < deg && (c * 16 + e) < deg)                           \
                alphaH[(size_t)(start + c * 16 + e) * 4 + hq] =               \
                    (unsigned short)bf16_rne(pc * inv);
        ALPHA_ST(0, p0) ALPHA_ST(1, p1) ALPHA_ST(2, p2) ALPHA_ST(3, p3)
        #undef ALPHA_ST
        if (e == 0) selfa[n * 4 + hq] = psel * inv;
    } else {
        float psum = 0.f;
        for (int i = start + e; i < end; i += 16) {
            int se = csr[i];
            float ev = a_src[se * 4 + hq] + ad;
            ev = (ev >= 0.f) ? ev : NSLOPE * ev;
            psum += __expf(ev);
        }
        psum += __shfl_xor(psum, 4);
        psum += __shfl_xor(psum, 8);
        psum += __shfl_xor(psum, 16);
        psum += __shfl_xor(psum, 32);
        const float inv = 1.f / (psum + psel);
        for (int i = start + e; i < end; i += 16) {
            int se = csr[i];
            float ev = a_src[se * 4 + hq] + ad;
            ev = (ev >= 0.f) ? ev : NSLOPE * ev;
            alphaH[(size_t)i * 4 + hq] = (unsigned short)bf16_rne(__expf(ev) * inv);
        }
        if (e == 0) selfa[n * 4 + hq] = psel * inv;
    }
}

// ---------------- Kernel 5: weighted gather-sum + fused classifier ----------
// Clamped 8-wide batches: always 8 gathers in flight, invalid slots alpha=0.
__global__ __launch_bounds__(256) void k_agg(
    const unsigned* __restrict__ h2, const unsigned* __restrict__ aP,
    const float* __restrict__ selfa, const int* __restrict__ rowptr,
    const int* __restrict__ csr, const float* __restrict__ b_gat,
    const float* __restrict__ W_lin, const float* __restrict__ b_lin,
    float* __restrict__ out, int N)
{
    const int t = threadIdx.x;
    const int wave = t >> 6, l = t & 63;
    const int n = blockIdx.x * 4 + wave;
    if (n >= N) return;

    const int start = rowptr[n], end = rowptr[n + 1];
    const int hA = l >> 5;   // 0/1; hB = 2+hA

    float acc0, acc1;
    {
        unsigned u = h2[(size_t)n * 64 + l];
        acc0 = selfa[n * 4 + hA] * bf_lo(u);
        acc1 = selfa[n * 4 + 2 + hA] * bf_hi(u);
    }

    for (int i = start; i < end; i += 8) {
        int sk[8]; float aA[8], aB[8]; unsigned u[8];
        #pragma unroll
        for (int k = 0; k < 8; ++k) {
            int j = i + k;
            bool vld = j < end;
            if (!vld) j = end - 1;
            sk[k] = csr[j];
            uint2 ap = *(const uint2*)(aP + (size_t)j * 2);
            float a0 = hA ? bf_hi(ap.x) : bf_lo(ap.x);
            float a1 = hA ? bf_hi(ap.y) : bf_lo(ap.y);
            aA[k] = vld ? a0 : 0.f;
            aB[k] = vld ? a1 : 0.f;
        }
        #pragma unroll
        for (int k = 0; k < 8; ++k) u[k] = h2[(size_t)sk[k] * 64 + l];
        #pragma unroll
        for (int k = 0; k < 8; ++k) {
            acc0 += aA[k] * bf_lo(u[k]);
            acc1 += aB[k] * bf_hi(u[k]);
        }
    }

    float r0 = fmaxf(acc0 + b_gat[l], 0.f);
    float r1 = fmaxf(acc1 + b_gat[64 + l], 0.f);
    float p0 = r0 * W_lin[l]       + r1 * W_lin[64 + l];
    float p1 = r0 * W_lin[128 + l] + r1 * W_lin[192 + l];
    #pragma unroll
    for (int m = 1; m < 64; m <<= 1) {
        p0 += __shfl_xor(p0, m);
        p1 += __shfl_xor(p1, m);
    }
    if (l == 0) {
        out[(size_t)n * 2]     = p0 + b_lin[0];
        out[(size_t)n * 2 + 1] = p1 + b_lin[1];
    }
}

// ---------------- launch ----------------
extern "C" void kernel_launch(void* const* d_in, const int* in_sizes, int n_in,
                              void* d_out, int out_size, void* d_ws, size_t ws_size,
                              hipStream_t stream)
{
    const float* x       = (const float*)d_in[0];
    const int*   ei      = (const int*)d_in[1];
    const float* Wg      = (const float*)d_in[2];
    const float* att_src = (const float*)d_in[3];
    const float* att_dst = (const float*)d_in[4];
    const float* b_gat   = (const float*)d_in[5];
    const float* W_lin   = (const float*)d_in[6];
    const float* b_lin   = (const float*)d_in[7];
    float* out = (float*)d_out;

    const int N = in_sizes[0] / 128;
    const int E = in_sizes[1] / 2;
    const int NBKT = (N + 127) >> 7;           // partition buckets (<=1024)
    const int NBLKA = 256;                     // partition blocks
    const int CHUNK = (E + NBLKA - 1) / NBLKA;

    // workspace layout
    char* ws = (char*)d_ws;
    unsigned* h2  = (unsigned*)ws;                    // N*64 packed bf16x2
    float* a_src  = (float*)(h2 + (size_t)N * 64);    // N*4
    float* a_dst  = a_src + (size_t)N * 4;            // N*4
    float* selfa  = a_dst + (size_t)N * 4;            // N*4
    int*   rowptr = (int*)(selfa + (size_t)N * 4);    // N+1
    int*   csr    = rowptr + (N + 1) + 3;             // E  (16B-align)
    unsigned short* alphaH = (unsigned short*)(csr + E); // E*4 bf16
    int*   M      = (int*)(alphaH + (size_t)E * 4);   // NBKT*NBLKA
    int*   bb     = M + (size_t)NBKT * NBLKA;         // NBKT+1
    unsigned* stage = (unsigned*)alphaH;              // alias (dead before k_alpha)

    k_gemm<<<512, 256, 0, stream>>>(x, Wg, h2, N);
    k_att<<<(N + 3) / 4, 256, 0, stream>>>(h2, att_src, att_dst, a_src, a_dst, N);
    k_partA<<<NBLKA, 256, 0, stream>>>(ei + E, M, E, NBKT, CHUNK);
    k_bscan<<<NBKT, 64, 0, stream>>>(M, bb, NBLKA);
    k_scan_part<<<1, 64, 0, stream>>>(bb, bb + NBKT, NBKT);
    k_partB<<<NBLKA, 256, 0, stream>>>(ei, M, bb, stage, E, NBKT, CHUNK);
    k_partC<<<NBKT, 256, 0, stream>>>(stage, bb, rowptr, csr, N, E);
    k_alpha<<<(N + 3) / 4, 256, 0, stream>>>(a_src, a_dst, rowptr, csr, alphaH, selfa, N);
    k_agg<<<(N + 3) / 4, 256, 0, stream>>>(h2, (const unsigned*)alphaH, selfa, rowptr, csr,
                                           b_gat, W_lin, b_lin, out, N);
}

// Round 7
// 197.887 us; speedup vs baseline: 2.4295x; 1.1207x over previous
//
#include <hip/hip_runtime.h>

#define NSLOPE  0.2f

typedef __attribute__((ext_vector_type(8))) short bf16x8;
typedef __attribute__((ext_vector_type(4))) float f32x4;

__device__ __forceinline__ unsigned bf16_rne(float f) {
    unsigned x = __float_as_uint(f);
    return (x + 0x7fffu + ((x >> 16) & 1u)) >> 16;
}
__device__ __forceinline__ float bf_lo(unsigned u) { return __uint_as_float(u << 16); }
__device__ __forceinline__ float bf_hi(unsigned u) { return __uint_as_float(u & 0xffff0000u); }

// ---------------- Kernel 1: h2 = bf16(x @ W^T) via MFMA ----------------
__global__ __launch_bounds__(256) void k_gemm(
    const float* __restrict__ x, const float* __restrict__ Wg,
    unsigned* __restrict__ h2, int N)
{
    __shared__ unsigned short Wl[128 * 136];   // bf16, rows=hc, cols=f

    const int t = threadIdx.x;
    const int wave = t >> 6, l = t & 63;

    for (int i = t; i < 128 * 32; i += 256) {
        int r = i >> 5, c4 = (i & 31) * 4;
        float4 w = *(const float4*)(Wg + r * 128 + c4);
        unsigned* wp = (unsigned*)((char*)Wl + r * 272 + c4 * 2);
        wp[0] = bf16_rne(w.x) | (bf16_rne(w.y) << 16);
        wp[1] = bf16_rne(w.z) | (bf16_rne(w.w) << 16);
    }
    __syncthreads();

    const int col = l & 15, kg = l >> 4;
    const int nwaves = gridDim.x * 4;
    const int wid = blockIdx.x * 4 + wave;

    for (int mb = wid * 16; mb < N; mb += nwaves * 16) {
        union { bf16x8 v; unsigned u[4]; } af[4];
        int row = mb + col; if (row >= N) row = N - 1;
        const float* xr = x + (size_t)row * 128 + kg * 8;
        #pragma unroll
        for (int s = 0; s < 4; ++s) {
            float4 xa = *(const float4*)(xr + s * 32);
            float4 xb = *(const float4*)(xr + s * 32 + 4);
            af[s].u[0] = bf16_rne(xa.x) | (bf16_rne(xa.y) << 16);
            af[s].u[1] = bf16_rne(xa.z) | (bf16_rne(xa.w) << 16);
            af[s].u[2] = bf16_rne(xb.x) | (bf16_rne(xb.y) << 16);
            af[s].u[3] = bf16_rne(xb.z) | (bf16_rne(xb.w) << 16);
        }

        f32x4 acc[8];
        #pragma unroll
        for (int tl = 0; tl < 8; ++tl) acc[tl] = (f32x4){0.f, 0.f, 0.f, 0.f};

        #pragma unroll
        for (int s = 0; s < 4; ++s) {
            #pragma unroll
            for (int tl = 0; tl < 8; ++tl) {
                const bf16x8 bf = *(const bf16x8*)((char*)Wl
                    + (tl * 16 + col) * 272 + (s * 32 + kg * 8) * 2);
                acc[tl] = __builtin_amdgcn_mfma_f32_16x16x32_bf16(af[s].v, bf, acc[tl], 0, 0, 0);
            }
        }

        #pragma unroll
        for (int tl = 0; tl < 4; ++tl) {
            #pragma unroll
            for (int r = 0; r < 4; ++r) {
                int node = mb + kg * 4 + r;
                if (node < N) {
                    unsigned w = bf16_rne(acc[tl][r]) | (bf16_rne(acc[tl + 4][r]) << 16);
                    h2[(size_t)node * 64 + tl * 16 + col] = w;
                }
            }
        }
    }
}

// ---------------- Kernel 1b: attention dots from h2 ----------------
__global__ __launch_bounds__(256) void k_att(
    const unsigned* __restrict__ h2, const float* __restrict__ att_src,
    const float* __restrict__ att_dst, float* __restrict__ a_src,
    float* __restrict__ a_dst, int N)
{
    const int t = threadIdx.x;
    const int wave = t >> 6, l = t & 63;
    const int n = blockIdx.x * 4 + wave;
    if (n >= N) return;

    unsigned u = h2[(size_t)n * 64 + l];
    float h0 = bf_lo(u), h1 = bf_hi(u);
    float ps = h0 * att_src[l],      pd = h0 * att_dst[l];
    float qs = h1 * att_src[64 + l], qd = h1 * att_dst[64 + l];
    #pragma unroll
    for (int m = 1; m < 32; m <<= 1) {
        ps += __shfl_xor(ps, m); pd += __shfl_xor(pd, m);
        qs += __shfl_xor(qs, m); qd += __shfl_xor(qd, m);
    }
    if (l == 0) {
        a_src[n * 4 + 0] = ps; a_dst[n * 4 + 0] = pd;
        a_src[n * 4 + 2] = qs; a_dst[n * 4 + 2] = qd;
    } else if (l == 32) {
        a_src[n * 4 + 1] = ps; a_dst[n * 4 + 1] = pd;
        a_src[n * 4 + 3] = qs; a_dst[n * 4 + 3] = qd;
    }
}

// ---------------- single-wave exclusive scan (bucket bases) ----------------
__global__ __launch_bounds__(64) void k_scan_part(
    int* __restrict__ partial, int* __restrict__ total_out, int nb)
{
    const int l = threadIdx.x;
    int carry = 0;
    for (int base = 0; base < nb; base += 64) {
        int i = base + l;
        int v = (i < nb) ? partial[i] : 0;
        int sc = v;
        #pragma unroll
        for (int m = 1; m < 64; m <<= 1) {
            int u = __shfl_up(sc, m);
            if (l >= m) sc += u;
        }
        if (i < nb) partial[i] = carry + sc - v;
        carry += __shfl(sc, 63);
    }
    if (l == 0) *total_out = carry;
}

// ---------------- CSR build: two-level counting sort ----------------
__global__ __launch_bounds__(256) void k_partA(
    const int* __restrict__ dst, int* __restrict__ M,
    int E, int nbkt, int chunk)
{
    __shared__ int hist[1024];
    for (int i = threadIdx.x; i < nbkt; i += 256) hist[i] = 0;
    __syncthreads();
    const int lo = blockIdx.x * chunk, hi = min(lo + chunk, E);
    for (int e = lo + threadIdx.x; e < hi; e += 256)
        atomicAdd(&hist[dst[e] >> 7], 1);
    __syncthreads();
    for (int i = threadIdx.x; i < nbkt; i += 256)
        M[(size_t)i * gridDim.x + blockIdx.x] = hist[i];
}

__global__ __launch_bounds__(64) void k_bscan(
    int* __restrict__ M, int* __restrict__ bb, int nblk)
{
    const int l = threadIdx.x;
    int* row = M + (size_t)blockIdx.x * nblk;
    int carry = 0;
    for (int base = 0; base < nblk; base += 64) {
        int i = base + l;
        int v = (i < nblk) ? row[i] : 0;
        int sc = v;
        #pragma unroll
        for (int m = 1; m < 64; m <<= 1) {
            int u = __shfl_up(sc, m);
            if (l >= m) sc += u;
        }
        if (i < nblk) row[i] = carry + sc - v;
        carry += __shfl(sc, 63);
    }
    if (l == 0) bb[blockIdx.x] = carry;
}

__global__ __launch_bounds__(256) void k_partB(
    const int* __restrict__ ei, const int* __restrict__ M,
    const int* __restrict__ bb, unsigned* __restrict__ stage,
    int E, int nbkt, int chunk)
{
    __shared__ int cur[1024];
    const int blk = blockIdx.x, nblk = gridDim.x;
    for (int i = threadIdx.x; i < nbkt; i += 256)
        cur[i] = M[(size_t)i * nblk + blk] + bb[i];
    __syncthreads();
    const int lo = blk * chunk, hi = min(lo + chunk, E);
    for (int e = lo + threadIdx.x; e < hi; e += 256) {
        int s = ei[e];
        int d = ei[E + e];
        int pos = atomicAdd(&cur[d >> 7], 1);
        stage[pos] = (unsigned)s | ((unsigned)(d & 127) << 25);
    }
}

__global__ __launch_bounds__(256) void k_partC(
    const unsigned* __restrict__ stage, const int* __restrict__ bb,
    int* __restrict__ rowptr, int* __restrict__ csr, int N, int E)
{
    __shared__ int cnt[128];
    __shared__ int cur[128];
    __shared__ int wtot;
    const int b = blockIdx.x, t = threadIdx.x;
    if (t < 128) cnt[t] = 0;
    __syncthreads();
    const int lo = bb[b], hi = bb[b + 1];
    for (int e = lo + t; e < hi; e += 256)
        atomicAdd(&cnt[stage[e] >> 25], 1);
    __syncthreads();
    int v = 0, sc = 0;
    const int l = t & 63;
    if (t < 128) {
        v = cnt[t];
        sc = v;
        #pragma unroll
        for (int m = 1; m < 64; m <<= 1) {
            int u = __shfl_up(sc, m);
            if (l >= m) sc += u;
        }
        if (t == 63) wtot = sc;
    }
    __syncthreads();
    if (t < 128) {
        int c = lo + sc - v + ((t >= 64) ? wtot : 0);
        cur[t] = c;
        int n = (b << 7) + t;
        if (n < N) rowptr[n] = c;
    }
    if (t == 0 && b == gridDim.x - 1) rowptr[N] = E;
    __syncthreads();
    for (int e = lo + t; e < hi; e += 256) {
        unsigned u = stage[e];
        int pos = atomicAdd(&cur[u >> 25], 1);
        csr[pos] = (int)(u & 0x1FFFFFFu);
    }
}

// ---------------- Kernel 4b: normalized alphas (bf16, address-foldable) -----
// Edge j stores two dwords: d0 = a_h0 | a_h2<<16, d1 = a_h1 | a_h3<<16.
// u16 slot for head hq: (hq&1)*2 + (hq>>1).
__global__ __launch_bounds__(256) void k_alpha(
    const float* __restrict__ a_src, const float* __restrict__ a_dst,
    const int* __restrict__ rowptr, const int* __restrict__ csr,
    unsigned short* __restrict__ alphaH, float* __restrict__ selfa, int N)
{
    const int t = threadIdx.x;
    const int wave = t >> 6, l = t & 63;
    const int n = blockIdx.x * 4 + wave;
    if (n >= N) return;

    const int start = rowptr[n], end = rowptr[n + 1];
    const int deg = end - start;
    const int e = l >> 2, hq = l & 3;
    const int slot = ((hq & 1) << 1) + (hq >> 1);
    const float ad = a_dst[n * 4 + hq];

    float evs = a_src[n * 4 + hq] + ad;
    evs = (evs >= 0.f) ? evs : NSLOPE * evs;
    const float psel = __expf(evs);

    if (deg <= 64) {
        float p0 = 0.f, p1 = 0.f, p2 = 0.f, p3 = 0.f;
        #define ALPHA_DO(c, pc)                                               \
            if (c * 16 < deg) {                                               \
                bool vv = (c * 16 + e) < deg;                                 \
                int se = vv ? csr[start + c * 16 + e] : 0;                    \
                float ev = a_src[se * 4 + hq] + ad;                           \
                ev = (ev >= 0.f) ? ev : NSLOPE * ev;                          \
                pc = vv ? __expf(ev) : 0.f;                                   \
            }
        ALPHA_DO(0, p0) ALPHA_DO(1, p1) ALPHA_DO(2, p2) ALPHA_DO(3, p3)
        #undef ALPHA_DO
        float psum = p0 + p1 + p2 + p3;
        psum += __shfl_xor(psum, 4);
        psum += __shfl_xor(psum, 8);
        psum += __shfl_xor(psum, 16);
        psum += __shfl_xor(psum, 32);
        const float inv = 1.f / (psum + psel);
        #define ALPHA_ST(c, pc)                                               \
            if (c * 16 < deg && (c * 16 + e) < deg)                           \
                alphaH[(size_t)(start + c * 16 + e) * 4 + slot] =             \
                    (unsigned short)bf16_rne(pc * inv);
        ALPHA_ST(0, p0) ALPHA_ST(1, p1) ALPHA_ST(2, p2) ALPHA_ST(3, p3)
        #undef ALPHA_ST
        if (e == 0) selfa[n * 4 + hq] = psel * inv;
    } else {
        float psum = 0.f;
        for (int i = start + e; i < end; i += 16) {
            int se = csr[i];
            float ev = a_src[se * 4 + hq] + ad;
            ev = (ev >= 0.f) ? ev : NSLOPE * ev;
            psum += __expf(ev);
        }
        psum += __shfl_xor(psum, 4);
        psum += __shfl_xor(psum, 8);
        psum += __shfl_xor(psum, 16);
        psum += __shfl_xor(psum, 32);
        const float inv = 1.f / (psum + psel);
        for (int i = start + e; i < end; i += 16) {
            int se = csr[i];
            float ev = a_src[se * 4 + hq] + ad;
            ev = (ev >= 0.f) ? ev : NSLOPE * ev;
            alphaH[(size_t)i * 4 + slot] = (unsigned short)bf16_rne(__expf(ev) * inv);
        }
        if (e == 0) selfa[n * 4 + hq] = psel * inv;
    }
}

// ---------------- Kernel 5: weighted gather-sum + fused classifier ----------
// Full 8-batches + scalar tail. Per edge per lane: csr dword (broadcast),
// one alpha dword (head-select folded into address), one h2 dword gather,
// 2 unpacks, 2 FMAs. No clamping, no cndmask.
__global__ __launch_bounds__(256) void k_agg(
    const unsigned* __restrict__ h2, const unsigned* __restrict__ aP,
    const float* __restrict__ selfa, const int* __restrict__ rowptr,
    const int* __restrict__ csr, const float* __restrict__ b_gat,
    const float* __restrict__ W_lin, const float* __restrict__ b_lin,
    float* __restrict__ out, int N)
{
    const int t = threadIdx.x;
    const int wave = t >> 6, l = t & 63;
    const int n = blockIdx.x * 4 + wave;
    if (n >= N) return;

    const int start = rowptr[n], end = rowptr[n + 1];
    const int hA = l >> 5;                        // 0/1; heads (hA, hA+2)
    const unsigned* aPh = aP + hA;                // fold head into base

    float acc0, acc1;
    {
        unsigned u = h2[(size_t)n * 64 + l];
        acc0 = selfa[n * 4 + hA] * bf_lo(u);
        acc1 = selfa[n * 4 + 2 + hA] * bf_hi(u);
    }

    int i = start;
    for (; i + 8 <= end; i += 8) {
        int sk[8]; unsigned d[8]; unsigned u[8];
        #pragma unroll
        for (int k = 0; k < 8; ++k) sk[k] = csr[i + k];
        #pragma unroll
        for (int k = 0; k < 8; ++k) d[k] = aPh[(size_t)(i + k) * 2];
        #pragma unroll
        for (int k = 0; k < 8; ++k) u[k] = h2[(size_t)sk[k] * 64 + l];
        #pragma unroll
        for (int k = 0; k < 8; ++k) {
            acc0 += bf_lo(d[k]) * bf_lo(u[k]);
            acc1 += bf_hi(d[k]) * bf_hi(u[k]);
        }
    }
    for (; i < end; ++i) {
        int s = csr[i];
        unsigned d = aPh[(size_t)i * 2];
        unsigned u = h2[(size_t)s * 64 + l];
        acc0 += bf_lo(d) * bf_lo(u);
        acc1 += bf_hi(d) * bf_hi(u);
    }

    float r0 = fmaxf(acc0 + b_gat[l], 0.f);
    float r1 = fmaxf(acc1 + b_gat[64 + l], 0.f);
    float p0 = r0 * W_lin[l]       + r1 * W_lin[64 + l];
    float p1 = r0 * W_lin[128 + l] + r1 * W_lin[192 + l];
    #pragma unroll
    for (int m = 1; m < 64; m <<= 1) {
        p0 += __shfl_xor(p0, m);
        p1 += __shfl_xor(p1, m);
    }
    if (l == 0) {
        out[(size_t)n * 2]     = p0 + b_lin[0];
        out[(size_t)n * 2 + 1] = p1 + b_lin[1];
    }
}

// ---------------- launch ----------------
extern "C" void kernel_launch(void* const* d_in, const int* in_sizes, int n_in,
                              void* d_out, int out_size, void* d_ws, size_t ws_size,
                              hipStream_t stream)
{
    const float* x       = (const float*)d_in[0];
    const int*   ei      = (const int*)d_in[1];
    const float* Wg      = (const float*)d_in[2];
    const float* att_src = (const float*)d_in[3];
    const float* att_dst = (const float*)d_in[4];
    const float* b_gat   = (const float*)d_in[5];
    const float* W_lin   = (const float*)d_in[6];
    const float* b_lin   = (const float*)d_in[7];
    float* out = (float*)d_out;

    const int N = in_sizes[0] / 128;
    const int E = in_sizes[1] / 2;
    const int NBKT = (N + 127) >> 7;           // partition buckets (<=1024)
    const int NBLKA = 256;                     // partition blocks
    const int CHUNK = (E + NBLKA - 1) / NBLKA;

    // workspace layout
    char* ws = (char*)d_ws;
    unsigned* h2  = (unsigned*)ws;                    // N*64 packed bf16x2
    float* a_src  = (float*)(h2 + (size_t)N * 64);    // N*4
    float* a_dst  = a_src + (size_t)N * 4;            // N*4
    float* selfa  = a_dst + (size_t)N * 4;            // N*4
    int*   rowptr = (int*)(selfa + (size_t)N * 4);    // N+1
    int*   csr    = rowptr + (N + 1) + 3;             // E  (16B-align)
    unsigned short* alphaH = (unsigned short*)(csr + E); // E*4 bf16
    int*   M      = (int*)(alphaH + (size_t)E * 4);   // NBKT*NBLKA
    int*   bb     = M + (size_t)NBKT * NBLKA;         // NBKT+1
    unsigned* stage = (unsigned*)alphaH;              // alias (dead before k_alpha)

    k_gemm<<<512, 256, 0, stream>>>(x, Wg, h2, N);
    k_att<<<(N + 3) / 4, 256, 0, stream>>>(h2, att_src, att_dst, a_src, a_dst, N);
    k_partA<<<NBLKA, 256, 0, stream>>>(ei + E, M, E, NBKT, CHUNK);
    k_bscan<<<NBKT, 64, 0, stream>>>(M, bb, NBLKA);
    k_scan_part<<<1, 64, 0, stream>>>(bb, bb + NBKT, NBKT);
    k_partB<<<NBLKA, 256, 0, stream>>>(ei, M, bb, stage, E, NBKT, CHUNK);
    k_partC<<<NBKT, 256, 0, stream>>>(stage, bb, rowptr, csr, N, E);
    k_alpha<<<(N + 3) / 4, 256, 0, stream>>>(a_src, a_dst, rowptr, csr, alphaH, selfa, N);
    k_agg<<<(N + 3) / 4, 256, 0, stream>>>(h2, (const unsigned*)alphaH, selfa, rowptr, csr,
                                           b_gat, W_lin, b_lin, out, N);
}

// Round 8
// 197.370 us; speedup vs baseline: 2.4358x; 1.0026x over previous
//
#include <hip/hip_runtime.h>

#define NSLOPE  0.2f

typedef __attribute__((ext_vector_type(8))) short bf16x8;
typedef __attribute__((ext_vector_type(4))) float f32x4;

__device__ __forceinline__ unsigned bf16_rne(float f) {
    unsigned x = __float_as_uint(f);
    return (x + 0x7fffu + ((x >> 16) & 1u)) >> 16;
}
__device__ __forceinline__ float bf_lo(unsigned u) { return __uint_as_float(u << 16); }
__device__ __forceinline__ float bf_hi(unsigned u) { return __uint_as_float(u & 0xffff0000u); }

// ---------------- Kernel 1: h2 = bf16(x @ W^T) via MFMA ----------------
__global__ __launch_bounds__(256) void k_gemm(
    const float* __restrict__ x, const float* __restrict__ Wg,
    unsigned* __restrict__ h2, int N)
{
    __shared__ unsigned short Wl[128 * 136];   // bf16, rows=hc, cols=f

    const int t = threadIdx.x;
    const int wave = t >> 6, l = t & 63;

    for (int i = t; i < 128 * 32; i += 256) {
        int r = i >> 5, c4 = (i & 31) * 4;
        float4 w = *(const float4*)(Wg + r * 128 + c4);
        unsigned* wp = (unsigned*)((char*)Wl + r * 272 + c4 * 2);
        wp[0] = bf16_rne(w.x) | (bf16_rne(w.y) << 16);
        wp[1] = bf16_rne(w.z) | (bf16_rne(w.w) << 16);
    }
    __syncthreads();

    const int col = l & 15, kg = l >> 4;
    const int nwaves = gridDim.x * 4;
    const int wid = blockIdx.x * 4 + wave;

    for (int mb = wid * 16; mb < N; mb += nwaves * 16) {
        union { bf16x8 v; unsigned u[4]; } af[4];
        int row = mb + col; if (row >= N) row = N - 1;
        const float* xr = x + (size_t)row * 128 + kg * 8;
        #pragma unroll
        for (int s = 0; s < 4; ++s) {
            float4 xa = *(const float4*)(xr + s * 32);
            float4 xb = *(const float4*)(xr + s * 32 + 4);
            af[s].u[0] = bf16_rne(xa.x) | (bf16_rne(xa.y) << 16);
            af[s].u[1] = bf16_rne(xa.z) | (bf16_rne(xa.w) << 16);
            af[s].u[2] = bf16_rne(xb.x) | (bf16_rne(xb.y) << 16);
            af[s].u[3] = bf16_rne(xb.z) | (bf16_rne(xb.w) << 16);
        }

        f32x4 acc[8];
        #pragma unroll
        for (int tl = 0; tl < 8; ++tl) acc[tl] = (f32x4){0.f, 0.f, 0.f, 0.f};

        #pragma unroll
        for (int s = 0; s < 4; ++s) {
            #pragma unroll
            for (int tl = 0; tl < 8; ++tl) {
                const bf16x8 bf = *(const bf16x8*)((char*)Wl
                    + (tl * 16 + col) * 272 + (s * 32 + kg * 8) * 2);
                acc[tl] = __builtin_amdgcn_mfma_f32_16x16x32_bf16(af[s].v, bf, acc[tl], 0, 0, 0);
            }
        }

        #pragma unroll
        for (int tl = 0; tl < 4; ++tl) {
            #pragma unroll
            for (int r = 0; r < 4; ++r) {
                int node = mb + kg * 4 + r;
                if (node < N) {
                    unsigned w = bf16_rne(acc[tl][r]) | (bf16_rne(acc[tl + 4][r]) << 16);
                    h2[(size_t)node * 64 + tl * 16 + col] = w;
                }
            }
        }
    }
}

// ---------------- Kernel 1b: attention dots from h2 ----------------
__global__ __launch_bounds__(256) void k_att(
    const unsigned* __restrict__ h2, const float* __restrict__ att_src,
    const float* __restrict__ att_dst, float* __restrict__ a_src,
    float* __restrict__ a_dst, int N)
{
    const int t = threadIdx.x;
    const int wave = t >> 6, l = t & 63;
    const int n = blockIdx.x * 4 + wave;
    if (n >= N) return;

    unsigned u = h2[(size_t)n * 64 + l];
    float h0 = bf_lo(u), h1 = bf_hi(u);
    float ps = h0 * att_src[l],      pd = h0 * att_dst[l];
    float qs = h1 * att_src[64 + l], qd = h1 * att_dst[64 + l];
    #pragma unroll
    for (int m = 1; m < 32; m <<= 1) {
        ps += __shfl_xor(ps, m); pd += __shfl_xor(pd, m);
        qs += __shfl_xor(qs, m); qd += __shfl_xor(qd, m);
    }
    if (l == 0) {
        a_src[n * 4 + 0] = ps; a_dst[n * 4 + 0] = pd;
        a_src[n * 4 + 2] = qs; a_dst[n * 4 + 2] = qd;
    } else if (l == 32) {
        a_src[n * 4 + 1] = ps; a_dst[n * 4 + 1] = pd;
        a_src[n * 4 + 3] = qs; a_dst[n * 4 + 3] = qd;
    }
}

// ---------------- single-wave exclusive scan (bucket bases) ----------------
__global__ __launch_bounds__(64) void k_scan_part(
    int* __restrict__ partial, int* __restrict__ total_out, int nb)
{
    const int l = threadIdx.x;
    int carry = 0;
    for (int base = 0; base < nb; base += 64) {
        int i = base + l;
        int v = (i < nb) ? partial[i] : 0;
        int sc = v;
        #pragma unroll
        for (int m = 1; m < 64; m <<= 1) {
            int u = __shfl_up(sc, m);
            if (l >= m) sc += u;
        }
        if (i < nb) partial[i] = carry + sc - v;
        carry += __shfl(sc, 63);
    }
    if (l == 0) *total_out = carry;
}

// ---------------- CSR build: two-level counting sort ----------------
__global__ __launch_bounds__(256) void k_partA(
    const int* __restrict__ dst, int* __restrict__ M,
    int E, int nbkt, int chunk)
{
    __shared__ int hist[1024];
    for (int i = threadIdx.x; i < nbkt; i += 256) hist[i] = 0;
    __syncthreads();
    const int lo = blockIdx.x * chunk, hi = min(lo + chunk, E);
    for (int e = lo + threadIdx.x; e < hi; e += 256)
        atomicAdd(&hist[dst[e] >> 7], 1);
    __syncthreads();
    for (int i = threadIdx.x; i < nbkt; i += 256)
        M[(size_t)i * gridDim.x + blockIdx.x] = hist[i];
}

__global__ __launch_bounds__(64) void k_bscan(
    int* __restrict__ M, int* __restrict__ bb, int nblk)
{
    const int l = threadIdx.x;
    int* row = M + (size_t)blockIdx.x * nblk;
    int carry = 0;
    for (int base = 0; base < nblk; base += 64) {
        int i = base + l;
        int v = (i < nblk) ? row[i] : 0;
        int sc = v;
        #pragma unroll
        for (int m = 1; m < 64; m <<= 1) {
            int u = __shfl_up(sc, m);
            if (l >= m) sc += u;
        }
        if (i < nblk) row[i] = carry + sc - v;
        carry += __shfl(sc, 63);
    }
    if (l == 0) bb[blockIdx.x] = carry;
}

__global__ __launch_bounds__(256) void k_partB(
    const int* __restrict__ ei, const int* __restrict__ M,
    const int* __restrict__ bb, unsigned* __restrict__ stage,
    int E, int nbkt, int chunk)
{
    __shared__ int cur[1024];
    const int blk = blockIdx.x, nblk = gridDim.x;
    for (int i = threadIdx.x; i < nbkt; i += 256)
        cur[i] = M[(size_t)i * nblk + blk] + bb[i];
    __syncthreads();
    const int lo = blk * chunk, hi = min(lo + chunk, E);
    for (int e = lo + threadIdx.x; e < hi; e += 256) {
        int s = ei[e];
        int d = ei[E + e];
        int pos = atomicAdd(&cur[d >> 7], 1);
        stage[pos] = (unsigned)s | ((unsigned)(d & 127) << 25);
    }
}

__global__ __launch_bounds__(256) void k_partC(
    const unsigned* __restrict__ stage, const int* __restrict__ bb,
    int* __restrict__ rowptr, int* __restrict__ csr, int N, int E)
{
    __shared__ int cnt[128];
    __shared__ int cur[128];
    __shared__ int wtot;
    const int b = blockIdx.x, t = threadIdx.x;
    if (t < 128) cnt[t] = 0;
    __syncthreads();
    const int lo = bb[b], hi = bb[b + 1];
    for (int e = lo + t; e < hi; e += 256)
        atomicAdd(&cnt[stage[e] >> 25], 1);
    __syncthreads();
    int v = 0, sc = 0;
    const int l = t & 63;
    if (t < 128) {
        v = cnt[t];
        sc = v;
        #pragma unroll
        for (int m = 1; m < 64; m <<= 1) {
            int u = __shfl_up(sc, m);
            if (l >= m) sc += u;
        }
        if (t == 63) wtot = sc;
    }
    __syncthreads();
    if (t < 128) {
        int c = lo + sc - v + ((t >= 64) ? wtot : 0);
        cur[t] = c;
        int n = (b << 7) + t;
        if (n < N) rowptr[n] = c;
    }
    if (t == 0 && b == gridDim.x - 1) rowptr[N] = E;
    __syncthreads();
    for (int e = lo + t; e < hi; e += 256) {
        unsigned u = stage[e];
        int pos = atomicAdd(&cur[u >> 25], 1);
        csr[pos] = (int)(u & 0x1FFFFFFu);
    }
}

// ---------------- Kernel 4b: normalized alphas (bf16, address-foldable) -----
// Edge j stores two dwords: d0 = a_h0 | a_h2<<16, d1 = a_h1 | a_h3<<16.
__global__ __launch_bounds__(256) void k_alpha(
    const float* __restrict__ a_src, const float* __restrict__ a_dst,
    const int* __restrict__ rowptr, const int* __restrict__ csr,
    unsigned short* __restrict__ alphaH, float* __restrict__ selfa, int N)
{
    const int t = threadIdx.x;
    const int wave = t >> 6, l = t & 63;
    const int n = blockIdx.x * 4 + wave;
    if (n >= N) return;

    const int start = rowptr[n], end = rowptr[n + 1];
    const int deg = end - start;
    const int e = l >> 2, hq = l & 3;
    const int slot = ((hq & 1) << 1) + (hq >> 1);
    const float ad = a_dst[n * 4 + hq];

    float evs = a_src[n * 4 + hq] + ad;
    evs = (evs >= 0.f) ? evs : NSLOPE * evs;
    const float psel = __expf(evs);

    if (deg <= 64) {
        float p0 = 0.f, p1 = 0.f, p2 = 0.f, p3 = 0.f;
        #define ALPHA_DO(c, pc)                                               \
            if (c * 16 < deg) {                                               \
                bool vv = (c * 16 + e) < deg;                                 \
                int se = vv ? csr[start + c * 16 + e] : 0;                    \
                float ev = a_src[se * 4 + hq] + ad;                           \
                ev = (ev >= 0.f) ? ev : NSLOPE * ev;                          \
                pc = vv ? __expf(ev) : 0.f;                                   \
            }
        ALPHA_DO(0, p0) ALPHA_DO(1, p1) ALPHA_DO(2, p2) ALPHA_DO(3, p3)
        #undef ALPHA_DO
        float psum = p0 + p1 + p2 + p3;
        psum += __shfl_xor(psum, 4);
        psum += __shfl_xor(psum, 8);
        psum += __shfl_xor(psum, 16);
        psum += __shfl_xor(psum, 32);
        const float inv = 1.f / (psum + psel);
        #define ALPHA_ST(c, pc)                                               \
            if (c * 16 < deg && (c * 16 + e) < deg)                           \
                alphaH[(size_t)(start + c * 16 + e) * 4 + slot] =             \
                    (unsigned short)bf16_rne(pc * inv);
        ALPHA_ST(0, p0) ALPHA_ST(1, p1) ALPHA_ST(2, p2) ALPHA_ST(3, p3)
        #undef ALPHA_ST
        if (e == 0) selfa[n * 4 + hq] = psel * inv;
    } else {
        float psum = 0.f;
        for (int i = start + e; i < end; i += 16) {
            int se = csr[i];
            float ev = a_src[se * 4 + hq] + ad;
            ev = (ev >= 0.f) ? ev : NSLOPE * ev;
            psum += __expf(ev);
        }
        psum += __shfl_xor(psum, 4);
        psum += __shfl_xor(psum, 8);
        psum += __shfl_xor(psum, 16);
        psum += __shfl_xor(psum, 32);
        const float inv = 1.f / (psum + psel);
        for (int i = start + e; i < end; i += 16) {
            int se = csr[i];
            float ev = a_src[se * 4 + hq] + ad;
            ev = (ev >= 0.f) ? ev : NSLOPE * ev;
            alphaH[(size_t)i * 4 + slot] = (unsigned short)bf16_rne(__expf(ev) * inv);
        }
        if (e == 0) selfa[n * 4 + hq] = psel * inv;
    }
}

// ---------------- Kernel 5: weighted gather-sum + fused classifier ----------
// 2 edges per wave: lane loads uint2 (dwords 2m,2m+1) of its half-wave's edge
// row; 32 lanes cover the 256B row. 8-deep batches span 16 edges. Head-pair
// select folded into the alpha address. Cross-half shfl reduce at the end.
__global__ __launch_bounds__(256) void k_agg(
    const unsigned* __restrict__ h2, const unsigned* __restrict__ aP,
    const float* __restrict__ selfa, const int* __restrict__ rowptr,
    const int* __restrict__ csr, const float* __restrict__ b_gat,
    const float* __restrict__ W_lin, const float* __restrict__ b_lin,
    float* __restrict__ out, int N)
{
    const int t = threadIdx.x;
    const int wave = t >> 6, l = t & 63;
    const int n = blockIdx.x * 4 + wave;
    if (n >= N) return;

    const int m    = l & 31;        // channel-pair group: dwords 2m, 2m+1
    const int half = l >> 5;        // which edge of the pair
    const int c0   = 2 * m;
    const int hsel = m >> 4;        // head pair (hsel, hsel+2)
    const unsigned* aPh = aP + hsel;

    const int start = rowptr[n], end = rowptr[n + 1];

    float a00 = 0.f, a01 = 0.f, a10 = 0.f, a11 = 0.f;

    int i = start;
    for (; i + 16 <= end; i += 16) {          // 8 slots x 2 edges
        int sk[8]; unsigned d[8]; uint2 u[8];
        #pragma unroll
        for (int k = 0; k < 8; ++k) {
            int j = i + 2 * k + half;
            sk[k] = csr[j];
            d[k]  = aPh[(size_t)j * 2];
        }
        #pragma unroll
        for (int k = 0; k < 8; ++k)
            u[k] = *(const uint2*)(h2 + (size_t)sk[k] * 64 + c0);
        #pragma unroll
        for (int k = 0; k < 8; ++k) {
            float wl = bf_lo(d[k]), wh = bf_hi(d[k]);
            a00 += wl * bf_lo(u[k].x); a01 += wh * bf_hi(u[k].x);
            a10 += wl * bf_lo(u[k].y); a11 += wh * bf_hi(u[k].y);
        }
    }
    if (i + 8 <= end) {                        // 4 slots x 2 edges
        int sk[4]; unsigned d[4]; uint2 u[4];
        #pragma unroll
        for (int k = 0; k < 4; ++k) {
            int j = i + 2 * k + half;
            sk[k] = csr[j];
            d[k]  = aPh[(size_t)j * 2];
        }
        #pragma unroll
        for (int k = 0; k < 4; ++k)
            u[k] = *(const uint2*)(h2 + (size_t)sk[k] * 64 + c0);
        #pragma unroll
        for (int k = 0; k < 4; ++k) {
            float wl = bf_lo(d[k]), wh = bf_hi(d[k]);
            a00 += wl * bf_lo(u[k].x); a01 += wh * bf_hi(u[k].x);
            a10 += wl * bf_lo(u[k].y); a11 += wh * bf_hi(u[k].y);
        }
        i += 8;
    }
    for (; i < end; i += 2) {                  // clamped pair tail (<4 iters)
        int j = i + half;
        bool vld = j < end;
        int jj = vld ? j : end - 1;
        int s = csr[jj];
        unsigned d = aPh[(size_t)jj * 2];
        d = vld ? d : 0u;
        uint2 u = *(const uint2*)(h2 + (size_t)s * 64 + c0);
        float wl = bf_lo(d), wh = bf_hi(d);
        a00 += wl * bf_lo(u.x); a01 += wh * bf_hi(u.x);
        a10 += wl * bf_lo(u.y); a11 += wh * bf_hi(u.y);
    }

    // cross-half reduce (edge pair)
    a00 += __shfl_xor(a00, 32);
    a01 += __shfl_xor(a01, 32);
    a10 += __shfl_xor(a10, 32);
    a11 += __shfl_xor(a11, 32);

    // self-loop (duplicated consistently on both halves)
    {
        uint2 u = *(const uint2*)(h2 + (size_t)n * 64 + c0);
        float sA = selfa[n * 4 + hsel];
        float sB = selfa[n * 4 + 2 + hsel];
        a00 += sA * bf_lo(u.x); a01 += sB * bf_hi(u.x);
        a10 += sA * bf_lo(u.y); a11 += sB * bf_hi(u.y);
    }

    // epilogue: channels c0, c0+64, c0+1, c0+65 (lanes 0-31 cover all 128)
    float r0 = fmaxf(a00 + b_gat[c0],      0.f);
    float r1 = fmaxf(a01 + b_gat[c0 + 64], 0.f);
    float r2 = fmaxf(a10 + b_gat[c0 + 1],  0.f);
    float r3 = fmaxf(a11 + b_gat[c0 + 65], 0.f);
    float p0 = r0 * W_lin[c0]       + r1 * W_lin[c0 + 64]
             + r2 * W_lin[c0 + 1]   + r3 * W_lin[c0 + 65];
    float p1 = r0 * W_lin[128 + c0]     + r1 * W_lin[128 + c0 + 64]
             + r2 * W_lin[128 + c0 + 1] + r3 * W_lin[128 + c0 + 65];
    #pragma unroll
    for (int s = 1; s < 32; s <<= 1) {
        p0 += __shfl_xor(p0, s);
        p1 += __shfl_xor(p1, s);
    }
    if (l == 0) {
        out[(size_t)n * 2]     = p0 + b_lin[0];
        out[(size_t)n * 2 + 1] = p1 + b_lin[1];
    }
}

// ---------------- launch ----------------
extern "C" void kernel_launch(void* const* d_in, const int* in_sizes, int n_in,
                              void* d_out, int out_size, void* d_ws, size_t ws_size,
                              hipStream_t stream)
{
    const float* x       = (const float*)d_in[0];
    const int*   ei      = (const int*)d_in[1];
    const float* Wg      = (const float*)d_in[2];
    const float* att_src = (const float*)d_in[3];
    const float* att_dst = (const float*)d_in[4];
    const float* b_gat   = (const float*)d_in[5];
    const float* W_lin   = (const float*)d_in[6];
    const float* b_lin   = (const float*)d_in[7];
    float* out = (float*)d_out;

    const int N = in_sizes[0] / 128;
    const int E = in_sizes[1] / 2;
    const int NBKT = (N + 127) >> 7;           // partition buckets (<=1024)
    const int NBLKA = 256;                     // partition blocks
    const int CHUNK = (E + NBLKA - 1) / NBLKA;

    // workspace layout
    char* ws = (char*)d_ws;
    unsigned* h2  = (unsigned*)ws;                    // N*64 packed bf16x2
    float* a_src  = (float*)(h2 + (size_t)N * 64);    // N*4
    float* a_dst  = a_src + (size_t)N * 4;            // N*4
    float* selfa  = a_dst + (size_t)N * 4;            // N*4
    int*   rowptr = (int*)(selfa + (size_t)N * 4);    // N+1
    int*   csr    = rowptr + (N + 1) + 3;             // E  (16B-align)
    unsigned short* alphaH = (unsigned short*)(csr + E); // E*4 bf16
    int*   M      = (int*)(alphaH + (size_t)E * 4);   // NBKT*NBLKA
    int*   bb     = M + (size_t)NBKT * NBLKA;         // NBKT+1
    unsigned* stage = (unsigned*)alphaH;              // alias (dead before k_alpha)

    k_gemm<<<512, 256, 0, stream>>>(x, Wg, h2, N);
    k_att<<<(N + 3) / 4, 256, 0, stream>>>(h2, att_src, att_dst, a_src, a_dst, N);
    k_partA<<<NBLKA, 256, 0, stream>>>(ei + E, M, E, NBKT, CHUNK);
    k_bscan<<<NBKT, 64, 0, stream>>>(M, bb, NBLKA);
    k_scan_part<<<1, 64, 0, stream>>>(bb, bb + NBKT, NBKT);
    k_partB<<<NBLKA, 256, 0, stream>>>(ei, M, bb, stage, E, NBKT, CHUNK);
    k_partC<<<NBKT, 256, 0, stream>>>(stage, bb, rowptr, csr, N, E);
    k_alpha<<<(N + 3) / 4, 256, 0, stream>>>(a_src, a_dst, rowptr, csr, alphaH, selfa, N);
    k_agg<<<(N + 3) / 4, 256, 0, stream>>>(h2, (const unsigned*)alphaH, selfa, rowptr, csr,
                                           b_gat, W_lin, b_lin, out, N);
}

// Round 9
// 192.613 us; speedup vs baseline: 2.4960x; 1.0247x over previous
//
#include <hip/hip_runtime.h>

#define NSLOPE  0.2f
#define LEXP(v) __expf((v) >= 0.f ? (v) : NSLOPE * (v))

typedef __attribute__((ext_vector_type(8))) short bf16x8;
typedef __attribute__((ext_vector_type(4))) float f32x4;

__device__ __forceinline__ unsigned bf16_rne(float f) {
    unsigned x = __float_as_uint(f);
    return (x + 0x7fffu + ((x >> 16) & 1u)) >> 16;
}
__device__ __forceinline__ float bf_lo(unsigned u) { return __uint_as_float(u << 16); }
__device__ __forceinline__ float bf_hi(unsigned u) { return __uint_as_float(u & 0xffff0000u); }

// ---------------- Kernel 1: h2 = bf16(x @ W^T) via MFMA + fused att dots ----
// D-layout: lane holds channel tl*16+col for nodes mb+kg*4+r. head = tl>>1.
__global__ __launch_bounds__(256) void k_gemm(
    const float* __restrict__ x, const float* __restrict__ Wg,
    const float* __restrict__ att_src, const float* __restrict__ att_dst,
    unsigned* __restrict__ h2, float* __restrict__ a_src, float* __restrict__ a_dst,
    int N)
{
    __shared__ unsigned short Wl[128 * 136];   // bf16, rows=hc, cols=f

    const int t = threadIdx.x;
    const int wave = t >> 6, l = t & 63;

    for (int i = t; i < 128 * 32; i += 256) {
        int r = i >> 5, c4 = (i & 31) * 4;
        float4 w = *(const float4*)(Wg + r * 128 + c4);
        unsigned* wp = (unsigned*)((char*)Wl + r * 272 + c4 * 2);
        wp[0] = bf16_rne(w.x) | (bf16_rne(w.y) << 16);
        wp[1] = bf16_rne(w.z) | (bf16_rne(w.w) << 16);
    }

    const int col = l & 15, kg = l >> 4;

    // per-lane att vectors for this lane's 8 channels (tl*16+col)
    float as8[8], ad8[8];
    #pragma unroll
    for (int tl = 0; tl < 8; ++tl) {
        as8[tl] = att_src[tl * 16 + col];
        ad8[tl] = att_dst[tl * 16 + col];
    }
    __syncthreads();

    const int nwaves = gridDim.x * 4;
    const int wid = blockIdx.x * 4 + wave;

    for (int mb = wid * 16; mb < N; mb += nwaves * 16) {
        union { bf16x8 v; unsigned u[4]; } af[4];
        int row = mb + col; if (row >= N) row = N - 1;
        const float* xr = x + (size_t)row * 128 + kg * 8;
        #pragma unroll
        for (int s = 0; s < 4; ++s) {
            float4 xa = *(const float4*)(xr + s * 32);
            float4 xb = *(const float4*)(xr + s * 32 + 4);
            af[s].u[0] = bf16_rne(xa.x) | (bf16_rne(xa.y) << 16);
            af[s].u[1] = bf16_rne(xa.z) | (bf16_rne(xa.w) << 16);
            af[s].u[2] = bf16_rne(xb.x) | (bf16_rne(xb.y) << 16);
            af[s].u[3] = bf16_rne(xb.z) | (bf16_rne(xb.w) << 16);
        }

        f32x4 acc[8];
        #pragma unroll
        for (int tl = 0; tl < 8; ++tl) acc[tl] = (f32x4){0.f, 0.f, 0.f, 0.f};

        #pragma unroll
        for (int s = 0; s < 4; ++s) {
            #pragma unroll
            for (int tl = 0; tl < 8; ++tl) {
                const bf16x8 bf = *(const bf16x8*)((char*)Wl
                    + (tl * 16 + col) * 272 + (s * 32 + kg * 8) * 2);
                acc[tl] = __builtin_amdgcn_mfma_f32_16x16x32_bf16(af[s].v, bf, acc[tl], 0, 0, 0);
            }
        }

        // pack channel pairs (c, c+64) and store
        #pragma unroll
        for (int tl = 0; tl < 4; ++tl) {
            #pragma unroll
            for (int r = 0; r < 4; ++r) {
                int node = mb + kg * 4 + r;
                if (node < N) {
                    unsigned w = bf16_rne(acc[tl][r]) | (bf16_rne(acc[tl + 4][r]) << 16);
                    h2[(size_t)node * 64 + tl * 16 + col] = w;
                }
            }
        }

        // fused attention dots: per node, head h sums tl=2h,2h+1 over 16 cols
        #pragma unroll
        for (int r = 0; r < 4; ++r) {
            int node = mb + kg * 4 + r;
            float s0 = acc[0][r] * as8[0] + acc[1][r] * as8[1];
            float s1 = acc[2][r] * as8[2] + acc[3][r] * as8[3];
            float s2 = acc[4][r] * as8[4] + acc[5][r] * as8[5];
            float s3 = acc[6][r] * as8[6] + acc[7][r] * as8[7];
            float d0 = acc[0][r] * ad8[0] + acc[1][r] * ad8[1];
            float d1 = acc[2][r] * ad8[2] + acc[3][r] * ad8[3];
            float d2 = acc[4][r] * ad8[4] + acc[5][r] * ad8[5];
            float d3 = acc[6][r] * ad8[6] + acc[7][r] * ad8[7];
            #pragma unroll
            for (int m = 1; m < 16; m <<= 1) {
                s0 += __shfl_xor(s0, m); s1 += __shfl_xor(s1, m);
                s2 += __shfl_xor(s2, m); s3 += __shfl_xor(s3, m);
                d0 += __shfl_xor(d0, m); d1 += __shfl_xor(d1, m);
                d2 += __shfl_xor(d2, m); d3 += __shfl_xor(d3, m);
            }
            if (col == 0 && node < N) {
                *(float4*)(a_src + (size_t)node * 4) = make_float4(s0, s1, s2, s3);
                *(float4*)(a_dst + (size_t)node * 4) = make_float4(d0, d1, d2, d3);
            }
        }
    }
}

// ---------------- single-wave exclusive scan (bucket bases) ----------------
__global__ __launch_bounds__(64) void k_scan_part(
    int* __restrict__ partial, int* __restrict__ total_out, int nb)
{
    const int l = threadIdx.x;
    int carry = 0;
    for (int base = 0; base < nb; base += 64) {
        int i = base + l;
        int v = (i < nb) ? partial[i] : 0;
        int sc = v;
        #pragma unroll
        for (int m = 1; m < 64; m <<= 1) {
            int u = __shfl_up(sc, m);
            if (l >= m) sc += u;
        }
        if (i < nb) partial[i] = carry + sc - v;
        carry += __shfl(sc, 63);
    }
    if (l == 0) *total_out = carry;
}

// ---------------- CSR build: two-level counting sort ----------------
__global__ __launch_bounds__(256) void k_partA(
    const int* __restrict__ dst, int* __restrict__ M,
    int E, int nbkt, int chunk)
{
    __shared__ int hist[1024];
    for (int i = threadIdx.x; i < nbkt; i += 256) hist[i] = 0;
    __syncthreads();
    const int lo = blockIdx.x * chunk, hi = min(lo + chunk, E);
    for (int e = lo + threadIdx.x; e < hi; e += 256)
        atomicAdd(&hist[dst[e] >> 7], 1);
    __syncthreads();
    for (int i = threadIdx.x; i < nbkt; i += 256)
        M[(size_t)i * gridDim.x + blockIdx.x] = hist[i];
}

__global__ __launch_bounds__(64) void k_bscan(
    int* __restrict__ M, int* __restrict__ bb, int nblk)
{
    const int l = threadIdx.x;
    int* row = M + (size_t)blockIdx.x * nblk;
    int carry = 0;
    for (int base = 0; base < nblk; base += 64) {
        int i = base + l;
        int v = (i < nblk) ? row[i] : 0;
        int sc = v;
        #pragma unroll
        for (int m = 1; m < 64; m <<= 1) {
            int u = __shfl_up(sc, m);
            if (l >= m) sc += u;
        }
        if (i < nblk) row[i] = carry + sc - v;
        carry += __shfl(sc, 63);
    }
    if (l == 0) bb[blockIdx.x] = carry;
}

__global__ __launch_bounds__(256) void k_partB(
    const int* __restrict__ ei, const int* __restrict__ M,
    const int* __restrict__ bb, unsigned* __restrict__ stage,
    int E, int nbkt, int chunk)
{
    __shared__ int cur[1024];
    const int blk = blockIdx.x, nblk = gridDim.x;
    for (int i = threadIdx.x; i < nbkt; i += 256)
        cur[i] = M[(size_t)i * nblk + blk] + bb[i];
    __syncthreads();
    const int lo = blk * chunk, hi = min(lo + chunk, E);
    for (int e = lo + threadIdx.x; e < hi; e += 256) {
        int s = ei[e];
        int d = ei[E + e];
        int pos = atomicAdd(&cur[d >> 7], 1);
        stage[pos] = (unsigned)s | ((unsigned)(d & 127) << 25);
    }
}

// Pass C: one block per bucket. Derives rowptr, sorts edges into csr, AND
// computes per-edge exps (bf16, unnormalized) + per-node denominators.
// alphaE[pos] = {exp_h0|exp_h2<<16, exp_h1|exp_h3<<16}. invD/selfa per node.
__global__ __launch_bounds__(256) void k_partC(
    const unsigned* __restrict__ stage, const int* __restrict__ bb,
    const float* __restrict__ a_src, const float* __restrict__ a_dst,
    int* __restrict__ rowptr, int* __restrict__ csr,
    unsigned* __restrict__ alphaE, float* __restrict__ selfa,
    float* __restrict__ invD, int N, int E)
{
    __shared__ int cnt[128];
    __shared__ int cur[128];
    __shared__ float adl[128][4];
    __shared__ float den[128][4];
    __shared__ int wtot;
    const int b = blockIdx.x, t = threadIdx.x;
    if (t < 128) {
        cnt[t] = 0;
        int n = (b << 7) + t;
        float4 v = (n < N) ? *(const float4*)(a_dst + (size_t)n * 4)
                           : make_float4(0.f, 0.f, 0.f, 0.f);
        *(float4*)adl[t] = v;
        *(float4*)den[t] = make_float4(0.f, 0.f, 0.f, 0.f);
    }
    __syncthreads();
    const int lo = bb[b], hi = bb[b + 1];
    for (int e = lo + t; e < hi; e += 256)
        atomicAdd(&cnt[stage[e] >> 25], 1);
    __syncthreads();
    int v = 0, sc = 0;
    const int l = t & 63;
    if (t < 128) {
        v = cnt[t];
        sc = v;
        #pragma unroll
        for (int m = 1; m < 64; m <<= 1) {
            int u = __shfl_up(sc, m);
            if (l >= m) sc += u;
        }
        if (t == 63) wtot = sc;
    }
    __syncthreads();
    if (t < 128) {
        int c = lo + sc - v + ((t >= 64) ? wtot : 0);
        cur[t] = c;
        int n = (b << 7) + t;
        if (n < N) rowptr[n] = c;
    }
    if (t == 0 && b == gridDim.x - 1) rowptr[N] = E;
    __syncthreads();
    for (int e = lo + t; e < hi; e += 256) {
        unsigned u = stage[e];
        int s  = (int)(u & 0x1FFFFFFu);
        int dl = (int)(u >> 25);
        float4 av = *(const float4*)(a_src + (size_t)s * 4);
        float x0 = LEXP(av.x + adl[dl][0]);
        float x1 = LEXP(av.y + adl[dl][1]);
        float x2 = LEXP(av.z + adl[dl][2]);
        float x3 = LEXP(av.w + adl[dl][3]);
        atomicAdd(&den[dl][0], x0);
        atomicAdd(&den[dl][1], x1);
        atomicAdd(&den[dl][2], x2);
        atomicAdd(&den[dl][3], x3);
        int pos = atomicAdd(&cur[dl], 1);
        csr[pos] = s;
        uint2 pk;
        pk.x = bf16_rne(x0) | (bf16_rne(x2) << 16);
        pk.y = bf16_rne(x1) | (bf16_rne(x3) << 16);
        *(uint2*)(alphaE + (size_t)pos * 2) = pk;
    }
    __syncthreads();
    if (t < 128) {
        int n = (b << 7) + t;
        if (n < N) {
            float4 av = *(const float4*)(a_src + (size_t)n * 4);
            float p0 = LEXP(av.x + adl[t][0]);
            float p1 = LEXP(av.y + adl[t][1]);
            float p2 = LEXP(av.z + adl[t][2]);
            float p3 = LEXP(av.w + adl[t][3]);
            float i0 = 1.f / (den[t][0] + p0);
            float i1 = 1.f / (den[t][1] + p1);
            float i2 = 1.f / (den[t][2] + p2);
            float i3 = 1.f / (den[t][3] + p3);
            *(float4*)(selfa + (size_t)n * 4) = make_float4(p0 * i0, p1 * i1, p2 * i2, p3 * i3);
            *(float4*)(invD  + (size_t)n * 4) = make_float4(i0, i1, i2, i3);
        }
    }
}

// ---------------- Kernel 5: weighted gather-sum + fused classifier ----------
// 2 edges per wave (uint2 row halves); unnormalized exps, scaled by invD at
// the end. Self-loop uses pre-normalized selfa.
__global__ __launch_bounds__(256) void k_agg(
    const unsigned* __restrict__ h2, const unsigned* __restrict__ aP,
    const float* __restrict__ selfa, const float* __restrict__ invD,
    const int* __restrict__ rowptr, const int* __restrict__ csr,
    const float* __restrict__ b_gat, const float* __restrict__ W_lin,
    const float* __restrict__ b_lin, float* __restrict__ out, int N)
{
    const int t = threadIdx.x;
    const int wave = t >> 6, l = t & 63;
    const int n = blockIdx.x * 4 + wave;
    if (n >= N) return;

    const int m    = l & 31;        // channel-pair group: dwords 2m, 2m+1
    const int half = l >> 5;        // which edge of the pair
    const int c0   = 2 * m;
    const int hsel = m >> 4;        // head pair (hsel, hsel+2)
    const unsigned* aPh = aP + hsel;

    const int start = rowptr[n], end = rowptr[n + 1];
    const float ivA = invD[n * 4 + hsel];
    const float ivB = invD[n * 4 + 2 + hsel];

    float a00 = 0.f, a01 = 0.f, a10 = 0.f, a11 = 0.f;

    int i = start;
    for (; i + 16 <= end; i += 16) {          // 8 slots x 2 edges
        int sk[8]; unsigned d[8]; uint2 u[8];
        #pragma unroll
        for (int k = 0; k < 8; ++k) {
            int j = i + 2 * k + half;
            sk[k] = csr[j];
            d[k]  = aPh[(size_t)j * 2];
        }
        #pragma unroll
        for (int k = 0; k < 8; ++k)
            u[k] = *(const uint2*)(h2 + (size_t)sk[k] * 64 + c0);
        #pragma unroll
        for (int k = 0; k < 8; ++k) {
            float wl = bf_lo(d[k]), wh = bf_hi(d[k]);
            a00 += wl * bf_lo(u[k].x); a01 += wh * bf_hi(u[k].x);
            a10 += wl * bf_lo(u[k].y); a11 += wh * bf_hi(u[k].y);
        }
    }
    if (i + 8 <= end) {                        // 4 slots x 2 edges
        int sk[4]; unsigned d[4]; uint2 u[4];
        #pragma unroll
        for (int k = 0; k < 4; ++k) {
            int j = i + 2 * k + half;
            sk[k] = csr[j];
            d[k]  = aPh[(size_t)j * 2];
        }
        #pragma unroll
        for (int k = 0; k < 4; ++k)
            u[k] = *(const uint2*)(h2 + (size_t)sk[k] * 64 + c0);
        #pragma unroll
        for (int k = 0; k < 4; ++k) {
            float wl = bf_lo(d[k]), wh = bf_hi(d[k]);
            a00 += wl * bf_lo(u[k].x); a01 += wh * bf_hi(u[k].x);
            a10 += wl * bf_lo(u[k].y); a11 += wh * bf_hi(u[k].y);
        }
        i += 8;
    }
    for (; i < end; i += 2) {                  // clamped pair tail (<4 iters)
        int j = i + half;
        bool vld = j < end;
        int jj = vld ? j : end - 1;
        int s = csr[jj];
        unsigned d = aPh[(size_t)jj * 2];
        d = vld ? d : 0u;
        uint2 u = *(const uint2*)(h2 + (size_t)s * 64 + c0);
        float wl = bf_lo(d), wh = bf_hi(d);
        a00 += wl * bf_lo(u.x); a01 += wh * bf_hi(u.x);
        a10 += wl * bf_lo(u.y); a11 += wh * bf_hi(u.y);
    }

    // cross-half reduce (edge pair), then normalize
    a00 += __shfl_xor(a00, 32);
    a01 += __shfl_xor(a01, 32);
    a10 += __shfl_xor(a10, 32);
    a11 += __shfl_xor(a11, 32);
    a00 *= ivA; a01 *= ivB; a10 *= ivA; a11 *= ivB;

    // self-loop (normalized alphas; duplicated consistently on both halves)
    {
        uint2 u = *(const uint2*)(h2 + (size_t)n * 64 + c0);
        float sA = selfa[n * 4 + hsel];
        float sB = selfa[n * 4 + 2 + hsel];
        a00 += sA * bf_lo(u.x); a01 += sB * bf_hi(u.x);
        a10 += sA * bf_lo(u.y); a11 += sB * bf_hi(u.y);
    }

    // epilogue: channels c0, c0+64, c0+1, c0+65 (lanes 0-31 cover all 128)
    float r0 = fmaxf(a00 + b_gat[c0],      0.f);
    float r1 = fmaxf(a01 + b_gat[c0 + 64], 0.f);
    float r2 = fmaxf(a10 + b_gat[c0 + 1],  0.f);
    float r3 = fmaxf(a11 + b_gat[c0 + 65], 0.f);
    float p0 = r0 * W_lin[c0]       + r1 * W_lin[c0 + 64]
             + r2 * W_lin[c0 + 1]   + r3 * W_lin[c0 + 65];
    float p1 = r0 * W_lin[128 + c0]     + r1 * W_lin[128 + c0 + 64]
             + r2 * W_lin[128 + c0 + 1] + r3 * W_lin[128 + c0 + 65];
    #pragma unroll
    for (int s = 1; s < 32; s <<= 1) {
        p0 += __shfl_xor(p0, s);
        p1 += __shfl_xor(p1, s);
    }
    if (l == 0) {
        out[(size_t)n * 2]     = p0 + b_lin[0];
        out[(size_t)n * 2 + 1] = p1 + b_lin[1];
    }
}

// ---------------- launch ----------------
extern "C" void kernel_launch(void* const* d_in, const int* in_sizes, int n_in,
                              void* d_out, int out_size, void* d_ws, size_t ws_size,
                              hipStream_t stream)
{
    const float* x       = (const float*)d_in[0];
    const int*   ei      = (const int*)d_in[1];
    const float* Wg      = (const float*)d_in[2];
    const float* att_src = (const float*)d_in[3];
    const float* att_dst = (const float*)d_in[4];
    const float* b_gat   = (const float*)d_in[5];
    const float* W_lin   = (const float*)d_in[6];
    const float* b_lin   = (const float*)d_in[7];
    float* out = (float*)d_out;

    const int N = in_sizes[0] / 128;
    const int E = in_sizes[1] / 2;
    const int NBKT = (N + 127) >> 7;           // partition buckets (<=1024)
    const int NBLKA = 256;                     // partition blocks
    const int CHUNK = (E + NBLKA - 1) / NBLKA;

    // workspace layout (no aliasing)
    char* ws = (char*)d_ws;
    unsigned* h2  = (unsigned*)ws;                    // N*64 packed bf16x2
    float* a_src  = (float*)(h2 + (size_t)N * 64);    // N*4
    float* a_dst  = a_src + (size_t)N * 4;            // N*4
    float* selfa  = a_dst + (size_t)N * 4;            // N*4
    float* invD   = selfa + (size_t)N * 4;            // N*4
    int*   rowptr = (int*)(invD + (size_t)N * 4);     // N+1
    int*   csr    = rowptr + (N + 1) + 3;             // E  (16B-align)
    unsigned* alphaE = (unsigned*)(csr + E);          // E*2 (bf16 exps x4)
    int*   M      = (int*)(alphaE + (size_t)E * 2);   // NBKT*NBLKA
    int*   bb     = M + (size_t)NBKT * NBLKA;         // NBKT+1
    unsigned* stage = (unsigned*)(bb + NBKT + 1);     // E

    k_gemm<<<512, 256, 0, stream>>>(x, Wg, att_src, att_dst, h2, a_src, a_dst, N);
    k_partA<<<NBLKA, 256, 0, stream>>>(ei + E, M, E, NBKT, CHUNK);
    k_bscan<<<NBKT, 64, 0, stream>>>(M, bb, NBLKA);
    k_scan_part<<<1, 64, 0, stream>>>(bb, bb + NBKT, NBKT);
    k_partB<<<NBLKA, 256, 0, stream>>>(ei, M, bb, stage, E, NBKT, CHUNK);
    k_partC<<<NBKT, 256, 0, stream>>>(stage, bb, a_src, a_dst, rowptr, csr,
                                      alphaE, selfa, invD, N, E);
    k_agg<<<(N + 3) / 4, 256, 0, stream>>>(h2, alphaE, selfa, invD, rowptr, csr,
                                           b_gat, W_lin, b_lin, out, N);
}

// Round 10
// 190.223 us; speedup vs baseline: 2.5273x; 1.0126x over previous
//
#include <hip/hip_runtime.h>

#define NSLOPE  0.2f
#define LEXP(v) __expf((v) >= 0.f ? (v) : NSLOPE * (v))

typedef __attribute__((ext_vector_type(8))) short bf16x8;
typedef __attribute__((ext_vector_type(4))) float f32x4;

__device__ __forceinline__ unsigned bf16_rne(float f) {
    unsigned x = __float_as_uint(f);
    return (x + 0x7fffu + ((x >> 16) & 1u)) >> 16;
}
__device__ __forceinline__ float bf_lo(unsigned u) { return __uint_as_float(u << 16); }
__device__ __forceinline__ float bf_hi(unsigned u) { return __uint_as_float(u & 0xffff0000u); }

// ---- Kernel 1 (fused): blocks [0,512): h2 = bf16(x@W^T) via MFMA, with
// attention dots via 4 extra MFMAs against watt = att@W (precomputed in LDS).
// Blocks [512, 512+nblkA): partA histogram role (hist aliases Wl).
__global__ __launch_bounds__(256) void k_gemm_partA(
    const float* __restrict__ x, const float* __restrict__ Wg,
    const float* __restrict__ att_src, const float* __restrict__ att_dst,
    unsigned* __restrict__ h2, float* __restrict__ a_src, float* __restrict__ a_dst,
    int N, const int* __restrict__ dst, int* __restrict__ M,
    int E, int nbkt, int chunk, int nblkA)
{
    __shared__ unsigned short Wl[128 * 136];   // bf16 W, rows=hc, cols=f (34.8KB)
    __shared__ unsigned short wattH[8][128];   // bf16 watt (2KB)

    const int t = threadIdx.x;

    if (blockIdx.x >= 512) {                   // ---- partA role ----
        const int blk = blockIdx.x - 512;
        int* hist = (int*)Wl;                  // alias
        for (int i = t; i < nbkt; i += 256) hist[i] = 0;
        __syncthreads();
        const int lo = blk * chunk, hi = min(lo + chunk, E);
        for (int e = lo + t; e < hi; e += 256)
            atomicAdd(&hist[dst[e] >> 7], 1);
        __syncthreads();
        for (int i = t; i < nbkt; i += 256)
            M[(size_t)i * nblkA + blk] = hist[i];
        return;
    }

    // ---- GEMM role ----
    for (int i = t; i < 128 * 32; i += 256) {
        int r = i >> 5, c4 = (i & 31) * 4;
        float4 w = *(const float4*)(Wg + r * 128 + c4);
        unsigned* wp = (unsigned*)((char*)Wl + r * 272 + c4 * 2);
        wp[0] = bf16_rne(w.x) | (bf16_rne(w.y) << 16);
        wp[1] = bf16_rne(w.z) | (bf16_rne(w.w) << 16);
    }
    // watt[j][f]: j<4 -> src head j; j>=4 -> dst head j-4   (1024 entries)
    for (int idx = t; idx < 1024; idx += 256) {
        int j = idx >> 7, f = idx & 127;
        const float* av = (j < 4) ? (att_src + j * 32) : (att_dst + (j - 4) * 32);
        int hh = (j & 3) * 32;
        float s = 0.f;
        #pragma unroll 8
        for (int k = 0; k < 32; ++k)
            s += av[k] * Wg[(size_t)(hh + k) * 128 + f];
        wattH[j][f] = (unsigned short)bf16_rne(s);
    }
    __syncthreads();

    const int wave = t >> 6, l = t & 63;
    const int col = l & 15, kg = l >> 4;

    // B fragments of watt (constant over the node loop)
    union { bf16x8 v; unsigned short s[8]; } batt[4];
    #pragma unroll
    for (int s4 = 0; s4 < 4; ++s4) {
        #pragma unroll
        for (int jj = 0; jj < 8; ++jj)
            batt[s4].s[jj] = (col < 8) ? wattH[col][s4 * 32 + kg * 8 + jj]
                                       : (unsigned short)0;
    }

    const int nwaves = 512 * 4;
    const int wid = blockIdx.x * 4 + wave;

    for (int mb = wid * 16; mb < N; mb += nwaves * 16) {
        union { bf16x8 v; unsigned u[4]; } af[4];
        int row = mb + col; if (row >= N) row = N - 1;
        const float* xr = x + (size_t)row * 128 + kg * 8;
        #pragma unroll
        for (int s = 0; s < 4; ++s) {
            float4 xa = *(const float4*)(xr + s * 32);
            float4 xb = *(const float4*)(xr + s * 32 + 4);
            af[s].u[0] = bf16_rne(xa.x) | (bf16_rne(xa.y) << 16);
            af[s].u[1] = bf16_rne(xa.z) | (bf16_rne(xa.w) << 16);
            af[s].u[2] = bf16_rne(xb.x) | (bf16_rne(xb.y) << 16);
            af[s].u[3] = bf16_rne(xb.z) | (bf16_rne(xb.w) << 16);
        }

        f32x4 acc[8];
        #pragma unroll
        for (int tl = 0; tl < 8; ++tl) acc[tl] = (f32x4){0.f, 0.f, 0.f, 0.f};
        f32x4 accd = (f32x4){0.f, 0.f, 0.f, 0.f};

        #pragma unroll
        for (int s = 0; s < 4; ++s) {
            #pragma unroll
            for (int tl = 0; tl < 8; ++tl) {
                const bf16x8 bf = *(const bf16x8*)((char*)Wl
                    + (tl * 16 + col) * 272 + (s * 32 + kg * 8) * 2);
                acc[tl] = __builtin_amdgcn_mfma_f32_16x16x32_bf16(af[s].v, bf, acc[tl], 0, 0, 0);
            }
            accd = __builtin_amdgcn_mfma_f32_16x16x32_bf16(af[s].v, batt[s].v, accd, 0, 0, 0);
        }

        // pack channel pairs (c, c+64) and store
        #pragma unroll
        for (int tl = 0; tl < 4; ++tl) {
            #pragma unroll
            for (int r = 0; r < 4; ++r) {
                int node = mb + kg * 4 + r;
                if (node < N) {
                    unsigned w = bf16_rne(acc[tl][r]) | (bf16_rne(acc[tl + 4][r]) << 16);
                    h2[(size_t)node * 64 + tl * 16 + col] = w;
                }
            }
        }
        // attention dots: lane (col=j<8, kg) holds dots for nodes kg*4+r
        if (col < 8) {
            float* bp = (col < 4) ? a_src : a_dst;
            const int j = col & 3;
            #pragma unroll
            for (int r = 0; r < 4; ++r) {
                int node = mb + kg * 4 + r;
                if (node < N) bp[(size_t)node * 4 + j] = accd[r];
            }
        }
    }
}

// ---------------- single-wave exclusive scan (bucket bases) ----------------
__global__ __launch_bounds__(64) void k_scan_part(
    int* __restrict__ partial, int* __restrict__ total_out, int nb)
{
    const int l = threadIdx.x;
    int carry = 0;
    for (int base = 0; base < nb; base += 64) {
        int i = base + l;
        int v = (i < nb) ? partial[i] : 0;
        int sc = v;
        #pragma unroll
        for (int m = 1; m < 64; m <<= 1) {
            int u = __shfl_up(sc, m);
            if (l >= m) sc += u;
        }
        if (i < nb) partial[i] = carry + sc - v;
        carry += __shfl(sc, 63);
    }
    if (l == 0) *total_out = carry;
}

__global__ __launch_bounds__(64) void k_bscan(
    int* __restrict__ M, int* __restrict__ bb, int nblk)
{
    const int l = threadIdx.x;
    int* row = M + (size_t)blockIdx.x * nblk;
    int carry = 0;
    for (int base = 0; base < nblk; base += 64) {
        int i = base + l;
        int v = (i < nblk) ? row[i] : 0;
        int sc = v;
        #pragma unroll
        for (int m = 1; m < 64; m <<= 1) {
            int u = __shfl_up(sc, m);
            if (l >= m) sc += u;
        }
        if (i < nblk) row[i] = carry + sc - v;
        carry += __shfl(sc, 63);
    }
    if (l == 0) bb[blockIdx.x] = carry;
}

__global__ __launch_bounds__(256) void k_partB(
    const int* __restrict__ ei, const int* __restrict__ M,
    const int* __restrict__ bb, unsigned* __restrict__ stage,
    int E, int nbkt, int chunk)
{
    __shared__ int cur[1024];
    const int blk = blockIdx.x, nblk = gridDim.x;
    for (int i = threadIdx.x; i < nbkt; i += 256)
        cur[i] = M[(size_t)i * nblk + blk] + bb[i];
    __syncthreads();
    const int lo = blk * chunk, hi = min(lo + chunk, E);
    for (int e = lo + threadIdx.x; e < hi; e += 256) {
        int s = ei[e];
        int d = ei[E + e];
        int pos = atomicAdd(&cur[d >> 7], 1);
        stage[pos] = (unsigned)s | ((unsigned)(d & 127) << 25);
    }
}

// Pass C: one block per bucket. Derives rowptr, sorts edges into csr, AND
// computes per-edge exps (bf16, unnormalized) + per-node denominators.
__global__ __launch_bounds__(256) void k_partC(
    const unsigned* __restrict__ stage, const int* __restrict__ bb,
    const float* __restrict__ a_src, const float* __restrict__ a_dst,
    int* __restrict__ rowptr, int* __restrict__ csr,
    unsigned* __restrict__ alphaE, float* __restrict__ selfa,
    float* __restrict__ invD, int N, int E)
{
    __shared__ int cnt[128];
    __shared__ int cur[128];
    __shared__ float adl[128][4];
    __shared__ float den[128][4];
    __shared__ int wtot;
    const int b = blockIdx.x, t = threadIdx.x;
    if (t < 128) {
        cnt[t] = 0;
        int n = (b << 7) + t;
        float4 v = (n < N) ? *(const float4*)(a_dst + (size_t)n * 4)
                           : make_float4(0.f, 0.f, 0.f, 0.f);
        *(float4*)adl[t] = v;
        *(float4*)den[t] = make_float4(0.f, 0.f, 0.f, 0.f);
    }
    __syncthreads();
    const int lo = bb[b], hi = bb[b + 1];
    for (int e = lo + t; e < hi; e += 256)
        atomicAdd(&cnt[stage[e] >> 25], 1);
    __syncthreads();
    int v = 0, sc = 0;
    const int l = t & 63;
    if (t < 128) {
        v = cnt[t];
        sc = v;
        #pragma unroll
        for (int m = 1; m < 64; m <<= 1) {
            int u = __shfl_up(sc, m);
            if (l >= m) sc += u;
        }
        if (t == 63) wtot = sc;
    }
    __syncthreads();
    if (t < 128) {
        int c = lo + sc - v + ((t >= 64) ? wtot : 0);
        cur[t] = c;
        int n = (b << 7) + t;
        if (n < N) rowptr[n] = c;
    }
    if (t == 0 && b == gridDim.x - 1) rowptr[N] = E;
    __syncthreads();
    for (int e = lo + t; e < hi; e += 256) {
        unsigned u = stage[e];
        int s  = (int)(u & 0x1FFFFFFu);
        int dl = (int)(u >> 25);
        float4 av = *(const float4*)(a_src + (size_t)s * 4);
        float x0 = LEXP(av.x + adl[dl][0]);
        float x1 = LEXP(av.y + adl[dl][1]);
        float x2 = LEXP(av.z + adl[dl][2]);
        float x3 = LEXP(av.w + adl[dl][3]);
        atomicAdd(&den[dl][0], x0);
        atomicAdd(&den[dl][1], x1);
        atomicAdd(&den[dl][2], x2);
        atomicAdd(&den[dl][3], x3);
        int pos = atomicAdd(&cur[dl], 1);
        csr[pos] = s;
        uint2 pk;
        pk.x = bf16_rne(x0) | (bf16_rne(x2) << 16);
        pk.y = bf16_rne(x1) | (bf16_rne(x3) << 16);
        *(uint2*)(alphaE + (size_t)pos * 2) = pk;
    }
    __syncthreads();
    if (t < 128) {
        int n = (b << 7) + t;
        if (n < N) {
            float4 av = *(const float4*)(a_src + (size_t)n * 4);
            float p0 = LEXP(av.x + adl[t][0]);
            float p1 = LEXP(av.y + adl[t][1]);
            float p2 = LEXP(av.z + adl[t][2]);
            float p3 = LEXP(av.w + adl[t][3]);
            float i0 = 1.f / (den[t][0] + p0);
            float i1 = 1.f / (den[t][1] + p1);
            float i2 = 1.f / (den[t][2] + p2);
            float i3 = 1.f / (den[t][3] + p3);
            *(float4*)(selfa + (size_t)n * 4) = make_float4(p0 * i0, p1 * i1, p2 * i2, p3 * i3);
            *(float4*)(invD  + (size_t)n * 4) = make_float4(i0, i1, i2, i3);
        }
    }
}

// ---------------- Kernel 5: weighted gather-sum + fused classifier ----------
__global__ __launch_bounds__(256) void k_agg(
    const unsigned* __restrict__ h2, const unsigned* __restrict__ aP,
    const float* __restrict__ selfa, const float* __restrict__ invD,
    const int* __restrict__ rowptr, const int* __restrict__ csr,
    const float* __restrict__ b_gat, const float* __restrict__ W_lin,
    const float* __restrict__ b_lin, float* __restrict__ out, int N)
{
    const int t = threadIdx.x;
    const int wave = t >> 6, l = t & 63;
    const int n = blockIdx.x * 4 + wave;
    if (n >= N) return;

    const int m    = l & 31;
    const int half = l >> 5;
    const int c0   = 2 * m;
    const int hsel = m >> 4;
    const unsigned* aPh = aP + hsel;

    const int start = rowptr[n], end = rowptr[n + 1];
    const float ivA = invD[n * 4 + hsel];
    const float ivB = invD[n * 4 + 2 + hsel];

    float a00 = 0.f, a01 = 0.f, a10 = 0.f, a11 = 0.f;

    int i = start;
    for (; i + 16 <= end; i += 16) {
        int sk[8]; unsigned d[8]; uint2 u[8];
        #pragma unroll
        for (int k = 0; k < 8; ++k) {
            int j = i + 2 * k + half;
            sk[k] = csr[j];
            d[k]  = aPh[(size_t)j * 2];
        }
        #pragma unroll
        for (int k = 0; k < 8; ++k)
            u[k] = *(const uint2*)(h2 + (size_t)sk[k] * 64 + c0);
        #pragma unroll
        for (int k = 0; k < 8; ++k) {
            float wl = bf_lo(d[k]), wh = bf_hi(d[k]);
            a00 += wl * bf_lo(u[k].x); a01 += wh * bf_hi(u[k].x);
            a10 += wl * bf_lo(u[k].y); a11 += wh * bf_hi(u[k].y);
        }
    }
    if (i + 8 <= end) {
        int sk[4]; unsigned d[4]; uint2 u[4];
        #pragma unroll
        for (int k = 0; k < 4; ++k) {
            int j = i + 2 * k + half;
            sk[k] = csr[j];
            d[k]  = aPh[(size_t)j * 2];
        }
        #pragma unroll
        for (int k = 0; k < 4; ++k)
            u[k] = *(const uint2*)(h2 + (size_t)sk[k] * 64 + c0);
        #pragma unroll
        for (int k = 0; k < 4; ++k) {
            float wl = bf_lo(d[k]), wh = bf_hi(d[k]);
            a00 += wl * bf_lo(u[k].x); a01 += wh * bf_hi(u[k].x);
            a10 += wl * bf_lo(u[k].y); a11 += wh * bf_hi(u[k].y);
        }
        i += 8;
    }
    for (; i < end; i += 2) {
        int j = i + half;
        bool vld = j < end;
        int jj = vld ? j : end - 1;
        int s = csr[jj];
        unsigned d = aPh[(size_t)jj * 2];
        d = vld ? d : 0u;
        uint2 u = *(const uint2*)(h2 + (size_t)s * 64 + c0);
        float wl = bf_lo(d), wh = bf_hi(d);
        a00 += wl * bf_lo(u.x); a01 += wh * bf_hi(u.x);
        a10 += wl * bf_lo(u.y); a11 += wh * bf_hi(u.y);
    }

    a00 += __shfl_xor(a00, 32);
    a01 += __shfl_xor(a01, 32);
    a10 += __shfl_xor(a10, 32);
    a11 += __shfl_xor(a11, 32);
    a00 *= ivA; a01 *= ivB; a10 *= ivA; a11 *= ivB;

    {
        uint2 u = *(const uint2*)(h2 + (size_t)n * 64 + c0);
        float sA = selfa[n * 4 + hsel];
        float sB = selfa[n * 4 + 2 + hsel];
        a00 += sA * bf_lo(u.x); a01 += sB * bf_hi(u.x);
        a10 += sA * bf_lo(u.y); a11 += sB * bf_hi(u.y);
    }

    float r0 = fmaxf(a00 + b_gat[c0],      0.f);
    float r1 = fmaxf(a01 + b_gat[c0 + 64], 0.f);
    float r2 = fmaxf(a10 + b_gat[c0 + 1],  0.f);
    float r3 = fmaxf(a11 + b_gat[c0 + 65], 0.f);
    float p0 = r0 * W_lin[c0]       + r1 * W_lin[c0 + 64]
             + r2 * W_lin[c0 + 1]   + r3 * W_lin[c0 + 65];
    float p1 = r0 * W_lin[128 + c0]     + r1 * W_lin[128 + c0 + 64]
             + r2 * W_lin[128 + c0 + 1] + r3 * W_lin[128 + c0 + 65];
    #pragma unroll
    for (int s = 1; s < 32; s <<= 1) {
        p0 += __shfl_xor(p0, s);
        p1 += __shfl_xor(p1, s);
    }
    if (l == 0) {
        out[(size_t)n * 2]     = p0 + b_lin[0];
        out[(size_t)n * 2 + 1] = p1 + b_lin[1];
    }
}

// ---------------- launch ----------------
extern "C" void kernel_launch(void* const* d_in, const int* in_sizes, int n_in,
                              void* d_out, int out_size, void* d_ws, size_t ws_size,
                              hipStream_t stream)
{
    const float* x       = (const float*)d_in[0];
    const int*   ei      = (const int*)d_in[1];
    const float* Wg      = (const float*)d_in[2];
    const float* att_src = (const float*)d_in[3];
    const float* att_dst = (const float*)d_in[4];
    const float* b_gat   = (const float*)d_in[5];
    const float* W_lin   = (const float*)d_in[6];
    const float* b_lin   = (const float*)d_in[7];
    float* out = (float*)d_out;

    const int N = in_sizes[0] / 128;
    const int E = in_sizes[1] / 2;
    const int NBKT = (N + 127) >> 7;
    const int NBLKA = 256;
    const int CHUNK = (E + NBLKA - 1) / NBLKA;

    // workspace layout (no aliasing)
    char* ws = (char*)d_ws;
    unsigned* h2  = (unsigned*)ws;                    // N*64 packed bf16x2
    float* a_src  = (float*)(h2 + (size_t)N * 64);    // N*4
    float* a_dst  = a_src + (size_t)N * 4;            // N*4
    float* selfa  = a_dst + (size_t)N * 4;            // N*4
    float* invD   = selfa + (size_t)N * 4;            // N*4
    int*   rowptr = (int*)(invD + (size_t)N * 4);     // N+1
    int*   csr    = rowptr + (N + 1) + 3;             // E  (16B-align)
    unsigned* alphaE = (unsigned*)(csr + E);          // E*2 (bf16 exps x4)
    int*   M      = (int*)(alphaE + (size_t)E * 2);   // NBKT*NBLKA
    int*   bb     = M + (size_t)NBKT * NBLKA;         // NBKT+1
    unsigned* stage = (unsigned*)(bb + NBKT + 1);     // E

    k_gemm_partA<<<512 + NBLKA, 256, 0, stream>>>(
        x, Wg, att_src, att_dst, h2, a_src, a_dst, N,
        ei + E, M, E, NBKT, CHUNK, NBLKA);
    k_bscan<<<NBKT, 64, 0, stream>>>(M, bb, NBLKA);
    k_scan_part<<<1, 64, 0, stream>>>(bb, bb + NBKT, NBKT);
    k_partB<<<NBLKA, 256, 0, stream>>>(ei, M, bb, stage, E, NBKT, CHUNK);
    k_partC<<<NBKT, 256, 0, stream>>>(stage, bb, a_src, a_dst, rowptr, csr,
                                      alphaE, selfa, invD, N, E);
    k_agg<<<(N + 3) / 4, 256, 0, stream>>>(h2, alphaE, selfa, invD, rowptr, csr,
                                           b_gat, W_lin, b_lin, out, N);
}